// Round 5
// baseline (1183.455 us; speedup 1.0000x reference)
//
#include <hip/hip_runtime.h>

typedef _Float16 f16;
typedef _Float16 f16x4 __attribute__((ext_vector_type(4)));
typedef _Float16 f16x8 __attribute__((ext_vector_type(8)));
typedef float f32x4 __attribute__((ext_vector_type(4)));

__device__ __forceinline__ float fast_rcp(float x) {
#if __has_builtin(__builtin_amdgcn_rcpf)
    return __builtin_amdgcn_rcpf(x);
#else
    return 1.0f / x;
#endif
}
__device__ __forceinline__ float sigmoidf(float x) { return fast_rcp(1.0f + __expf(-x)); }
__device__ __forceinline__ float tanh_f(float x)   { return 2.0f * fast_rcp(1.0f + __expf(-2.0f * x)) - 1.0f; }

// ===========================================================================
// ws layout (f32 units):
//  h_catT  0        786432   [t][b][384]
//  xconvT  786432   262144   [b][feat][w]
//  Pf      1048576  524288
//  Qf      1572864  524288
//  Pt      2097152  524288
//  Qt      2621440  524288
//  giF     3145728  786432   f16 frag-linear [t][tau][lane][r]; reused enc->dec
//  w_ihB   3932160  147456   f16 frags [tau48][kk12][lane][8]
//  whhE    4079616  98304    f16 frags [tau48][kk8][lane][8]
//  whhD    4177920  98304
//  dwihB   4276224  98304
//  linTf   4374528  65536
//  linTt   4440064  65536
//  recT    4505600  32768
//  h_end   4538368  4096
//  dec_out 4542464  524288   (aliased as convT early: conv reads before gru_dec writes)
// tau = jt*3 + g ; n = g*256 + jt*16 + lq ; k = kk*32 + quad*8 + e
// ===========================================================================

// ---------------------------------------------------------------------------
// K0: prep — weight transposes + MFMA B-fragment images (one-time, parallel)
// grid 3392 x 64
// ---------------------------------------------------------------------------
__global__ void prep_kernel(const float* __restrict__ conv_w,
                            const float* __restrict__ fg_lin_w,
                            const float* __restrict__ tg_lin_w,
                            const float* __restrict__ w_ih,
                            const float* __restrict__ w_hh,
                            const float* __restrict__ dec_w_ih,
                            const float* __restrict__ dec_w_hh,
                            const float* __restrict__ rec_fc_w,
                            f16* __restrict__ w_ihB, f16* __restrict__ whhE,
                            f16* __restrict__ whhD, f16* __restrict__ dwihB,
                            float* __restrict__ linTf, float* __restrict__ linTt,
                            float* __restrict__ recT, float* __restrict__ convT)
{
    const int blk = blockIdx.x, lane = threadIdx.x;
    const int quad = lane >> 4, lq = lane & 15;
    if (blk < 576) {                       // w_ihB (K=384)
        int tau = blk / 12, kk = blk % 12;
        int g = tau % 3, jt = tau / 3;
        int n = g * 256 + jt * 16 + lq;
        int k0 = kk * 32 + quad * 8;
        f16x8 v;
#pragma unroll
        for (int e = 0; e < 8; ++e) v[e] = (f16)w_ih[n * 384 + k0 + e];
        *(f16x8*)&w_ihB[(blk * 64 + lane) * 8] = v;
    } else if (blk < 1344) {               // whhE / whhD (K=256)
        int i = blk - 576;
        const float* src = w_hh; f16* dst = whhE;
        if (i >= 384) { i -= 384; src = dec_w_hh; dst = whhD; }
        int tau = i / 8, kk = i % 8;
        int g = tau % 3, jt = tau / 3;
        int n = g * 256 + jt * 16 + lq;
        int k0 = kk * 32 + quad * 8;
        f16x8 v;
#pragma unroll
        for (int e = 0; e < 8; ++e) v[e] = (f16)src[n * 256 + k0 + e];
        *(f16x8*)&dst[(i * 64 + lane) * 8] = v;
    } else if (blk < 1728) {               // dwihB (K=256)
        int i = blk - 1344;
        int tau = i / 8, kk = i % 8;
        int g = tau % 3, jt = tau / 3;
        int n = g * 256 + jt * 16 + lq;
        int k0 = kk * 32 + quad * 8;
        f16x8 v;
#pragma unroll
        for (int e = 0; e < 8; ++e) v[e] = (f16)dec_w_ih[n * 256 + k0 + e];
        *(f16x8*)&dwihB[(i * 64 + lane) * 8] = v;
    } else if (blk < 2240) {               // lin transposes
        int i = blk - 1728; int mat = i >> 8, d = i & 255;
        const float* src = mat ? tg_lin_w : fg_lin_w;
        float* dst = mat ? linTt : linTf;
#pragma unroll
        for (int c = 0; c < 4; ++c) { int n = lane + 64 * c; dst[d * 256 + n] = src[n * 256 + d]; }
    } else if (blk < 2496) {               // recT
        int d = blk - 2240;
#pragma unroll
        for (int c = 0; c < 2; ++c) { int j2 = lane + 64 * c; recT[d * 128 + j2] = rec_fc_w[j2 * 256 + d]; }
    } else {                               // convT, blk < 3392
        int i = blk - 2496;
#pragma unroll
        for (int c = 0; c < 2; ++c) { int co = lane + 64 * c; convT[i * 128 + co] = conv_w[co * 896 + i]; }
    }
}

// ---------------------------------------------------------------------------
// K1: Conv1d (KS=7, pad 3) + ReLU -> h_catT[t][b][0:128] and xconvT[b][feat][w]
// grid (wc=16, b=16), block 128; weights coalesced via convT
// ---------------------------------------------------------------------------
__global__ void conv_kernel(const float* __restrict__ x,
                            const float* __restrict__ convT,
                            const float* __restrict__ cb,
                            float* __restrict__ h_catT,
                            float* __restrict__ xconvT)
{
    const int wc = blockIdx.x, b = blockIdx.y, tid = threadIdx.x;
    __shared__ float xs[14][128];
    const int w0 = wc * 8;
#pragma unroll
    for (int i = 0; i < 14; ++i) {
        int row = w0 - 3 + i;
        xs[i][tid] = (row >= 0 && row < 128) ? x[(b * 128 + row) * 128 + tid] : 0.f;
    }
    __syncthreads();
    float bias = cb[tid];
    float acc[8];
#pragma unroll
    for (int j = 0; j < 8; ++j) acc[j] = bias;
    for (int ci = 0; ci < 128; ++ci) {
        float wv[7];
#pragma unroll
        for (int t = 0; t < 7; ++t) wv[t] = convT[(ci * 7 + t) * 128 + tid];
#pragma unroll
        for (int t = 0; t < 7; ++t) {
#pragma unroll
            for (int j = 0; j < 8; ++j) acc[j] += xs[j + t][ci] * wv[t];
        }
    }
#pragma unroll
    for (int j = 0; j < 8; ++j) {
        float v = fmaxf(acc[j], 0.f);
        h_catT[((w0 + j) * 16 + b) * 384 + tid] = v;
        xconvT[(b * 128 + tid) * 128 + w0 + j] = v;
    }
}

// ---------------------------------------------------------------------------
// K2: GATv2 lin projection, factored: P = v@Wl^T + b, Q = v@Wr^T
// grid 256 (8 rows each), block 256 (thread = n). Coalesced transposed weights.
// mode0: v rows flat from xconvT; mode1: v = h_catT[t][b][0:128]
// ---------------------------------------------------------------------------
__global__ void lin_kernel(const float* __restrict__ vsrc, int mode,
                           const float* __restrict__ T,
                           const float* __restrict__ lb,
                           float* __restrict__ P, float* __restrict__ Q)
{
    const int tid = threadIdx.x;
    const int row0 = blockIdx.x * 8;
    __shared__ __align__(16) float vs[8][128];
    if (mode == 0) {
        ((float4*)vs)[tid] = ((const float4*)(vsrc + row0 * 128))[tid];
    } else {
        int b = row0 >> 7;
        int rr = tid >> 5, q = tid & 31;
        int t = (row0 & 127) + rr;
        *(float4*)&vs[rr][q * 4] = *(const float4*)&vsrc[(t * 16 + b) * 384 + q * 4];
    }
    __syncthreads();
    const int n = tid;
    float bias = lb[n];
    float accP[8], accQ[8];
#pragma unroll
    for (int rr = 0; rr < 8; ++rr) { accP[rr] = bias; accQ[rr] = 0.f; }
    for (int d4 = 0; d4 < 32; ++d4) {
        float4 vv[8];
#pragma unroll
        for (int rr = 0; rr < 8; ++rr) vv[rr] = *(const float4*)&vs[rr][d4 * 4];
#pragma unroll
        for (int e = 0; e < 4; ++e) {
            float wP = T[(d4 * 4 + e) * 256 + n];
            float wQ = T[(128 + d4 * 4 + e) * 256 + n];
#pragma unroll
            for (int rr = 0; rr < 8; ++rr) {
                float h = (e == 0) ? vv[rr].x : (e == 1) ? vv[rr].y : (e == 2) ? vv[rr].z : vv[rr].w;
                accP[rr] += h * wP;
                accQ[rr] += h * wQ;
            }
        }
    }
#pragma unroll
    for (int rr = 0; rr < 8; ++rr) {
        P[(long)(row0 + rr) * 256 + n] = accP[rr];
        Q[(long)(row0 + rr) * 256 + n] = accQ[rr];
    }
}

// ---------------------------------------------------------------------------
// K3: GAT attention. grid 2048 (b,i), block 256. attn@v from LDS-staged v-tile.
// mode0 out -> h_catT[.][128+i]; mode1 out -> h_catT[.][256+d]
// ---------------------------------------------------------------------------
__global__ void gat_kernel(const float* __restrict__ P, const float* __restrict__ Q,
                           const float* __restrict__ a,
                           const float* __restrict__ bias,
                           const float* __restrict__ vbase,
                           float* __restrict__ h_catT, int mode)
{
    const int bid = blockIdx.x;
    const int b = bid >> 7, i = bid & 127;
    const int tid = threadIdx.x;
    __shared__ __align__(16) float Ps[256], as_[256], ej[128], red[8], op[256];
    __shared__ __align__(16) float buf[16384];   // Qs (32x264) then v-tile (128x128)

    Ps[tid]  = P[(long)(b * 128 + i) * 256 + tid];
    as_[tid] = a[tid];

    const int jl = tid >> 3, c = tid & 7;
    for (int j0 = 0; j0 < 128; j0 += 32) {
        __syncthreads();
#pragma unroll
        for (int r = 0; r < 8; ++r) {
            int flat = r * 256 + tid;
            int jj = flat >> 6, e4 = flat & 63;
            *(float4*)&buf[jj * 264 + e4 * 4] =
                *(const float4*)&Q[(long)(b * 128 + j0 + jj) * 256 + e4 * 4];
        }
        __syncthreads();
        float p = 0.f;
        for (int k = 0; k < 32; ++k) {
            int e = c + 8 * k;
            float hv = Ps[e] + buf[jl * 264 + e];
            hv = (hv > 0.f) ? hv : 0.2f * hv;
            p += hv * as_[e];
        }
        p += __shfl_xor(p, 1);
        p += __shfl_xor(p, 2);
        p += __shfl_xor(p, 4);
        if (c == 0) ej[j0 + jl] = p + bias[i * 128 + j0 + jl];
    }
    __syncthreads();
    {   // softmax over 128
        float v = (tid < 128) ? ej[tid] : -1e30f;
#pragma unroll
        for (int off = 32; off >= 1; off >>= 1) v = fmaxf(v, __shfl_xor(v, off));
        if ((tid & 63) == 0) red[tid >> 6] = v;
        __syncthreads();
        float m = fmaxf(fmaxf(red[0], red[1]), fmaxf(red[2], red[3]));
        float p = (tid < 128) ? __expf(ej[tid] - m) : 0.f;
        float s = p;
#pragma unroll
        for (int off = 32; off >= 1; off >>= 1) s += __shfl_xor(s, off);
        if ((tid & 63) == 0) red[4 + (tid >> 6)] = s;
        __syncthreads();
        float rs = fast_rcp(red[4] + red[5] + red[6] + red[7]);
        if (tid < 128) ej[tid] = p * rs;
        __syncthreads();
    }
    // stage v-tile [128 nodes][128 d] into LDS (reuses buf; Qs is dead)
    if (mode == 0) {
        const float4* s = (const float4*)(vbase + (long)b * 16384);
#pragma unroll
        for (int i2 = 0; i2 < 16; ++i2) ((float4*)buf)[i2 * 256 + tid] = s[i2 * 256 + tid];
    } else {
        int row = tid >> 1, hf = tid & 1;
#pragma unroll
        for (int i2 = 0; i2 < 16; ++i2) {
            int cc = (hf * 16 + i2) * 4;
            *(float4*)&buf[row * 128 + cc] = *(const float4*)&vbase[(row * 16 + b) * 384 + cc];
        }
    }
    __syncthreads();
    // out = sigmoid(attn @ v) from LDS
    const int half = tid >> 7, d = tid & 127;
    float p0 = 0.f, p1 = 0.f, p2 = 0.f, p3 = 0.f;
#pragma unroll 4
    for (int j = 0; j < 64; j += 4) {
        int jb = half * 64 + j;
        p0 += ej[jb]     * buf[(jb)     * 128 + d];
        p1 += ej[jb + 1] * buf[(jb + 1) * 128 + d];
        p2 += ej[jb + 2] * buf[(jb + 2) * 128 + d];
        p3 += ej[jb + 3] * buf[(jb + 3) * 128 + d];
    }
    op[tid] = (p0 + p1) + (p2 + p3);
    __syncthreads();
    if (tid < 128) {
        float o = sigmoidf(op[tid] + op[tid + 128]);
        if (mode == 0)
            h_catT[(tid * 16 + b) * 384 + 128 + i] = o;
        else
            h_catT[(i * 16 + b) * 384 + 256 + tid] = o;
    }
}

// ---------------------------------------------------------------------------
// K4: gi GEMM via MFMA: gi = h_cat @ w_ih^T + (b_ih + b_hh[r,z]); output in
// C-fragment-linear f16 layout giF[t][tau][lane][r]. grid 128 (t), block 256.
// ---------------------------------------------------------------------------
__global__ void __launch_bounds__(256)
gi_gemm(const float* __restrict__ h_catT, const f16* __restrict__ w_ihB,
        const float* __restrict__ b_ih, const float* __restrict__ b_hh,
        f16* __restrict__ giF)
{
    const int t = blockIdx.x, tid = threadIdx.x;
    const int w = tid >> 6, lane = tid & 63, quad = lane >> 4, lq = lane & 15;
    __shared__ __align__(16) f16 hA[16][392];
    {
        int rr = tid >> 4, ii = tid & 15;
#pragma unroll
        for (int i2 = 0; i2 < 6; ++i2) {
            int cc = (ii * 6 + i2) * 4;
            float4 v = *(const float4*)&h_catT[(t * 16 + rr) * 384 + cc];
            f16x4 h; h[0] = (f16)v.x; h[1] = (f16)v.y; h[2] = (f16)v.z; h[3] = (f16)v.w;
            *(f16x4*)&hA[rr][cc] = h;
        }
    }
    float biasv[12];
#pragma unroll
    for (int ti = 0; ti < 12; ++ti) {
        int tau = w * 12 + ti, g = tau % 3, jt = tau / 3;
        int n = g * 256 + jt * 16 + lq;
        biasv[ti] = b_ih[n] + (g < 2 ? b_hh[n] : 0.f);
    }
    f32x4 acc[12] = {};
    __syncthreads();
    for (int kk = 0; kk < 12; ++kk) {
        f16x8 A = *(const f16x8*)&hA[lq][kk * 32 + quad * 8];
#pragma unroll
        for (int ti = 0; ti < 12; ++ti) {
            f16x8 B = *(const f16x8*)&w_ihB[(((w * 12 + ti) * 12 + kk) * 64 + lane) * 8];
            acc[ti] = __builtin_amdgcn_mfma_f32_16x16x32_f16(A, B, acc[ti], 0, 0, 0);
        }
    }
#pragma unroll
    for (int ti = 0; ti < 12; ++ti) {
        f16x4 o;
#pragma unroll
        for (int r = 0; r < 4; ++r) o[r] = (f16)(acc[ti][r] + biasv[ti]);
        *(f16x4*)&giF[((t * 48 + w * 12 + ti) * 64 + lane) * 4] = o;
    }
}

// ---------------------------------------------------------------------------
// K4b: decoder-input GEMM: gi_dec[m][n] = he[m][2t]*W[:, :128]s + he[m][2t+1]*...
// repeat_interleave makes A[m][k] constant per k-half -> splat A-frags, no LDS.
// grid 128 (t), block 256. Output giF (same frag layout, reused buffer).
// ---------------------------------------------------------------------------
__global__ void __launch_bounds__(256)
gi_dec_gemm(const float* __restrict__ h_end, const f16* __restrict__ dwihB,
            const float* __restrict__ dec_b_ih, const float* __restrict__ dec_b_hh,
            f16* __restrict__ giF)
{
    const int t = blockIdx.x, tid = threadIdx.x;
    const int w = tid >> 6, lane = tid & 63, lq = lane & 15;
    float2 e = *(const float2*)&h_end[lq * 256 + 2 * t];
    f16 e0 = (f16)e.x, e1 = (f16)e.y;
    f16x8 A0, A1;
#pragma unroll
    for (int k = 0; k < 8; ++k) { A0[k] = e0; A1[k] = e1; }
    float biasv[12];
#pragma unroll
    for (int ti = 0; ti < 12; ++ti) {
        int tau = w * 12 + ti, g = tau % 3, jt = tau / 3;
        int n = g * 256 + jt * 16 + lq;
        biasv[ti] = dec_b_ih[n] + (g < 2 ? dec_b_hh[n] : 0.f);
    }
    f32x4 acc[12] = {};
    for (int kk = 0; kk < 8; ++kk) {
        f16x8 A = (kk < 4) ? A0 : A1;
#pragma unroll
        for (int ti = 0; ti < 12; ++ti) {
            f16x8 B = *(const f16x8*)&dwihB[(((w * 12 + ti) * 8 + kk) * 64 + lane) * 8];
            acc[ti] = __builtin_amdgcn_mfma_f32_16x16x32_f16(A, B, acc[ti], 0, 0, 0);
        }
    }
#pragma unroll
    for (int ti = 0; ti < 12; ++ti) {
        f16x4 o;
#pragma unroll
        for (int r = 0; r < 4; ++r) o[r] = (f16)(acc[ti][r] + biasv[ti]);
        *(f16x4*)&giF[((t * 48 + w * 12 + ti) * 64 + lane) * 4] = o;
    }
}

// ---------------------------------------------------------------------------
// K5: GRU recurrence via MFMA, 1 block x 512 thr (8 waves, 2/SIMD).
// M=16 batches fills the 16x16x32_f16 tile; w_hh lives in 192 regs as B-frags;
// h round-trips LDS as f16 A-frags (8 ds_read_b128/wave/step). gi read from
// frag-linear giF (coalesced 8B loads). One barrier/step.
// ---------------------------------------------------------------------------
__global__ void __launch_bounds__(512, 2)
gru_half(const f16* __restrict__ giF, const f16* __restrict__ whhF,
         const float* __restrict__ b_hh_full,
         float* __restrict__ h_end, float* __restrict__ dec_out, int is_dec)
{
    const int tid = threadIdx.x;
    const int w = tid >> 6, lane = tid & 63, quad = lane >> 4, lq = lane & 15;
    __shared__ __align__(16) f16 hA[2][16][264];
    for (int i = tid; i < 16 * 264; i += 512) hA[0][0][i] = (f16)0.f;

    f16x8 Bf[6][8];
#pragma unroll
    for (int ti = 0; ti < 6; ++ti)
#pragma unroll
        for (int kk = 0; kk < 8; ++kk)
            Bf[ti][kk] = *(const f16x8*)&whhF[(((w * 6 + ti) * 8 + kk) * 64 + lane) * 8];
    float bhn[2];
#pragma unroll
    for (int jg = 0; jg < 2; ++jg) bhn[jg] = b_hh_full[512 + (2 * w + jg) * 16 + lq];
    float hreg[2][4] = {};
    const f16x4* gp = (const f16x4*)giF;
    __syncthreads();

    for (int t = 0; t < 128; ++t) {
        const int par = t & 1;
        f16x4 gv[6];
#pragma unroll
        for (int ti = 0; ti < 6; ++ti) gv[ti] = gp[(t * 48 + w * 6 + ti) * 64 + lane];
        f32x4 acc[6] = {};
#pragma unroll
        for (int kk = 0; kk < 8; ++kk) {
            f16x8 A = *(const f16x8*)&hA[par][lq][kk * 32 + quad * 8];
#pragma unroll
            for (int ti = 0; ti < 6; ++ti)
                acc[ti] = __builtin_amdgcn_mfma_f32_16x16x32_f16(A, Bf[ti][kk], acc[ti], 0, 0, 0);
        }
#pragma unroll
        for (int jg = 0; jg < 2; ++jg) {
            const int j = (2 * w + jg) * 16 + lq;
#pragma unroll
            for (int r = 0; r < 4; ++r) {
                const int m = quad * 4 + r;
                float gr = sigmoidf((float)gv[jg * 3 + 0][r] + acc[jg * 3 + 0][r]);
                float gz = sigmoidf((float)gv[jg * 3 + 1][r] + acc[jg * 3 + 1][r]);
                float gn = tanh_f((float)gv[jg * 3 + 2][r] + gr * (acc[jg * 3 + 2][r] + bhn[jg]));
                float hn = (1.f - gz) * gn + gz * hreg[jg][r];
                hreg[jg][r] = hn;
                hA[par ^ 1][m][j] = (f16)hn;
                if (is_dec) dec_out[(m * 128 + t) * 256 + j] = hn;
            }
        }
        __syncthreads();
    }
    if (!is_dec) {
#pragma unroll
        for (int jg = 0; jg < 2; ++jg)
#pragma unroll
            for (int r = 0; r < 4; ++r)
                h_end[(quad * 4 + r) * 256 + (2 * w + jg) * 16 + lq] = hreg[jg][r];
    }
}

// ---------------------------------------------------------------------------
// K6: forecast MLP. grid 16, block 256.
// ---------------------------------------------------------------------------
__global__ void mlp_kernel(const float* __restrict__ h_end,
                           const float* __restrict__ fc1_w,
                           const float* __restrict__ fc1_b,
                           const float* __restrict__ fc2_w,
                           const float* __restrict__ fc2_b,
                           float* __restrict__ out)
{
    const int b = blockIdx.x, tid = threadIdx.x;
    __shared__ __align__(16) float hv[256], hid[256];
    hv[tid] = h_end[b * 256 + tid];
    __syncthreads();
    float acc = fc1_b[tid], acc2 = 0.f;
    const float4* wr = (const float4*)(fc1_w + tid * 256);
#pragma unroll 4
    for (int i = 0; i < 64; i += 2) {
        float4 w0 = wr[i], w1 = wr[i + 1];
        float4 h0 = *(const float4*)&hv[i * 4], h1 = *(const float4*)&hv[i * 4 + 4];
        acc  += w0.x * h0.x + w0.y * h0.y + w0.z * h0.z + w0.w * h0.w;
        acc2 += w1.x * h1.x + w1.y * h1.y + w1.z * h1.z + w1.w * h1.w;
    }
    hid[tid] = fmaxf(acc + acc2, 0.f);
    __syncthreads();
    if (tid < 128) {
        float a2 = fc2_b[tid], a3 = 0.f;
        const float4* w2 = (const float4*)(fc2_w + tid * 256);
#pragma unroll 4
        for (int i = 0; i < 64; i += 2) {
            float4 w0 = w2[i], w1 = w2[i + 1];
            float4 h0 = *(const float4*)&hid[i * 4], h1 = *(const float4*)&hid[i * 4 + 4];
            a2 += w0.x * h0.x + w0.y * h0.y + w0.z * h0.z + w0.w * h0.w;
            a3 += w1.x * h1.x + w1.y * h1.y + w1.z * h1.z + w1.w * h1.w;
        }
        out[b * 128 + tid] = a2 + a3;
    }
}

// ---------------------------------------------------------------------------
// K7: recons = dec_out @ rec_fc_w^T + b. grid 256 (8 rows), block 256.
// ---------------------------------------------------------------------------
__global__ void recon_kernel(const float* __restrict__ dec_out,
                             const float* __restrict__ recT,
                             const float* __restrict__ rec_b,
                             float* __restrict__ out)
{
    const int blk = blockIdx.x, tid = threadIdx.x;
    __shared__ __align__(16) float dv[8][256];
#pragma unroll
    for (int i = 0; i < 2; ++i)
        ((float4*)dv)[i * 256 + tid] = ((const float4*)(dec_out + blk * 2048))[i * 256 + tid];
    __syncthreads();
    const int j = tid & 127, rh = tid >> 7;
    float acc[4];
#pragma unroll
    for (int rr = 0; rr < 4; ++rr) acc[rr] = rec_b[j];
    for (int d4 = 0; d4 < 64; ++d4) {
        float4 vv[4];
#pragma unroll
        for (int rr = 0; rr < 4; ++rr) vv[rr] = *(const float4*)&dv[rh * 4 + rr][d4 * 4];
#pragma unroll
        for (int e = 0; e < 4; ++e) {
            float wv = recT[(d4 * 4 + e) * 128 + j];
#pragma unroll
            for (int rr = 0; rr < 4; ++rr) {
                float h = (e == 0) ? vv[rr].x : (e == 1) ? vv[rr].y : (e == 2) ? vv[rr].z : vv[rr].w;
                acc[rr] += h * wv;
            }
        }
    }
#pragma unroll
    for (int rr = 0; rr < 4; ++rr)
        out[(blk * 8 + rh * 4 + rr) * 128 + j] = acc[rr];
}

// ---------------------------------------------------------------------------
extern "C" void kernel_launch(void* const* d_in, const int* in_sizes, int n_in,
                              void* d_out, int out_size, void* d_ws, size_t ws_size,
                              hipStream_t stream)
{
    const float* x        = (const float*)d_in[0];
    const float* conv_w   = (const float*)d_in[1];
    const float* conv_b   = (const float*)d_in[2];
    const float* fg_lin_w = (const float*)d_in[3];
    const float* fg_lin_b = (const float*)d_in[4];
    const float* fg_a     = (const float*)d_in[5];
    const float* fg_bias  = (const float*)d_in[6];
    const float* tg_lin_w = (const float*)d_in[7];
    const float* tg_lin_b = (const float*)d_in[8];
    const float* tg_a     = (const float*)d_in[9];
    const float* tg_bias  = (const float*)d_in[10];
    const float* gru_w_ih = (const float*)d_in[11];
    const float* gru_w_hh = (const float*)d_in[12];
    const float* gru_b_ih = (const float*)d_in[13];
    const float* gru_b_hh = (const float*)d_in[14];
    const float* fc1_w    = (const float*)d_in[15];
    const float* fc1_b    = (const float*)d_in[16];
    const float* fc2_w    = (const float*)d_in[17];
    const float* fc2_b    = (const float*)d_in[18];
    const float* dec_w_ih = (const float*)d_in[19];
    const float* dec_w_hh = (const float*)d_in[20];
    const float* dec_b_ih = (const float*)d_in[21];
    const float* dec_b_hh = (const float*)d_in[22];
    const float* rec_fc_w = (const float*)d_in[23];
    const float* rec_fc_b = (const float*)d_in[24];
    float* out = (float*)d_out;

    float* ws      = (float*)d_ws;
    float* h_catT  = ws;
    float* xconvT  = ws + 786432;
    float* Pf      = ws + 1048576;
    float* Qf      = ws + 1572864;
    float* Pt      = ws + 2097152;
    float* Qt      = ws + 2621440;
    f16*   giF     = (f16*)(ws + 3145728);
    f16*   w_ihB   = (f16*)(ws + 3932160);
    f16*   whhE    = (f16*)(ws + 4079616);
    f16*   whhD    = (f16*)(ws + 4177920);
    f16*   dwihB   = (f16*)(ws + 4276224);
    float* linTf   = ws + 4374528;
    float* linTt   = ws + 4440064;
    float* recT    = ws + 4505600;
    float* h_end   = ws + 4538368;
    float* dec_out = ws + 4542464;
    float* convT   = dec_out;   // alias: conv reads before gru_dec writes dec_out

    prep_kernel<<<3392, 64, 0, stream>>>(conv_w, fg_lin_w, tg_lin_w, gru_w_ih, gru_w_hh,
                                         dec_w_ih, dec_w_hh, rec_fc_w,
                                         w_ihB, whhE, whhD, dwihB, linTf, linTt, recT, convT);
    conv_kernel<<<dim3(16, 16), 128, 0, stream>>>(x, convT, conv_b, h_catT, xconvT);
    lin_kernel<<<256, 256, 0, stream>>>(xconvT, 0, linTf, fg_lin_b, Pf, Qf);
    lin_kernel<<<256, 256, 0, stream>>>(h_catT, 1, linTt, tg_lin_b, Pt, Qt);
    gat_kernel<<<2048, 256, 0, stream>>>(Pf, Qf, fg_a, fg_bias, xconvT, h_catT, 0);
    gat_kernel<<<2048, 256, 0, stream>>>(Pt, Qt, tg_a, tg_bias, h_catT, h_catT, 1);
    gi_gemm<<<128, 256, 0, stream>>>(h_catT, w_ihB, gru_b_ih, gru_b_hh, giF);
    gru_half<<<1, 512, 0, stream>>>(giF, whhE, gru_b_hh, h_end, dec_out, 0);
    gi_dec_gemm<<<128, 256, 0, stream>>>(h_end, dwihB, dec_b_ih, dec_b_hh, giF);
    mlp_kernel<<<16, 256, 0, stream>>>(h_end, fc1_w, fc1_b, fc2_w, fc2_b, out);
    gru_half<<<1, 512, 0, stream>>>(giF, whhD, dec_b_hh, h_end, dec_out, 1);
    recon_kernel<<<256, 256, 0, stream>>>(dec_out, recT, rec_fc_b, out + 2048);
}

// Round 6
// 1084.729 us; speedup vs baseline: 1.0910x; 1.0910x over previous
//
#include <hip/hip_runtime.h>

typedef _Float16 f16;
typedef _Float16 f16x4 __attribute__((ext_vector_type(4)));
typedef _Float16 f16x8 __attribute__((ext_vector_type(8)));
typedef float f32x4 __attribute__((ext_vector_type(4)));

__device__ __forceinline__ float fast_rcp(float x) {
#if __has_builtin(__builtin_amdgcn_rcpf)
    return __builtin_amdgcn_rcpf(x);
#else
    return 1.0f / x;
#endif
}
__device__ __forceinline__ float sigmoidf(float x) { return fast_rcp(1.0f + __expf(-x)); }
__device__ __forceinline__ float tanh_f(float x)   { return 2.0f * fast_rcp(1.0f + __expf(-2.0f * x)) - 1.0f; }

// ===========================================================================
// ws layout (f32 units) — see R5; unchanged.
// tau = jt*3 + g ; n = g*256 + jt*16 + lq ; k = kk*32 + quad*8 + e
// ===========================================================================

// ---------------------------------------------------------------------------
// K0: prep — weight transposes + MFMA B-fragment images (one-time, parallel)
// ---------------------------------------------------------------------------
__global__ void prep_kernel(const float* __restrict__ conv_w,
                            const float* __restrict__ fg_lin_w,
                            const float* __restrict__ tg_lin_w,
                            const float* __restrict__ w_ih,
                            const float* __restrict__ w_hh,
                            const float* __restrict__ dec_w_ih,
                            const float* __restrict__ dec_w_hh,
                            const float* __restrict__ rec_fc_w,
                            f16* __restrict__ w_ihB, f16* __restrict__ whhE,
                            f16* __restrict__ whhD, f16* __restrict__ dwihB,
                            float* __restrict__ linTf, float* __restrict__ linTt,
                            float* __restrict__ recT, float* __restrict__ convT)
{
    const int blk = blockIdx.x, lane = threadIdx.x;
    const int quad = lane >> 4, lq = lane & 15;
    if (blk < 576) {                       // w_ihB (K=384)
        int tau = blk / 12, kk = blk % 12;
        int g = tau % 3, jt = tau / 3;
        int n = g * 256 + jt * 16 + lq;
        int k0 = kk * 32 + quad * 8;
        f16x8 v;
#pragma unroll
        for (int e = 0; e < 8; ++e) v[e] = (f16)w_ih[n * 384 + k0 + e];
        *(f16x8*)&w_ihB[(blk * 64 + lane) * 8] = v;
    } else if (blk < 1344) {               // whhE / whhD (K=256)
        int i = blk - 576;
        const float* src = w_hh; f16* dst = whhE;
        if (i >= 384) { i -= 384; src = dec_w_hh; dst = whhD; }
        int tau = i / 8, kk = i % 8;
        int g = tau % 3, jt = tau / 3;
        int n = g * 256 + jt * 16 + lq;
        int k0 = kk * 32 + quad * 8;
        f16x8 v;
#pragma unroll
        for (int e = 0; e < 8; ++e) v[e] = (f16)src[n * 256 + k0 + e];
        *(f16x8*)&dst[(i * 64 + lane) * 8] = v;
    } else if (blk < 1728) {               // dwihB (K=256)
        int i = blk - 1344;
        int tau = i / 8, kk = i % 8;
        int g = tau % 3, jt = tau / 3;
        int n = g * 256 + jt * 16 + lq;
        int k0 = kk * 32 + quad * 8;
        f16x8 v;
#pragma unroll
        for (int e = 0; e < 8; ++e) v[e] = (f16)dec_w_ih[n * 256 + k0 + e];
        *(f16x8*)&dwihB[(i * 64 + lane) * 8] = v;
    } else if (blk < 2240) {               // lin transposes
        int i = blk - 1728; int mat = i >> 8, d = i & 255;
        const float* src = mat ? tg_lin_w : fg_lin_w;
        float* dst = mat ? linTt : linTf;
#pragma unroll
        for (int c = 0; c < 4; ++c) { int n = lane + 64 * c; dst[d * 256 + n] = src[n * 256 + d]; }
    } else if (blk < 2496) {               // recT
        int d = blk - 2240;
#pragma unroll
        for (int c = 0; c < 2; ++c) { int j2 = lane + 64 * c; recT[d * 128 + j2] = rec_fc_w[j2 * 256 + d]; }
    } else {                               // convT, blk < 3392
        int i = blk - 2496;
#pragma unroll
        for (int c = 0; c < 2; ++c) { int co = lane + 64 * c; convT[i * 128 + co] = conv_w[co * 896 + i]; }
    }
}

// ---------------------------------------------------------------------------
// K1: Conv1d (KS=7, pad 3) + ReLU -> h_catT[t][b][0:128] and xconvT[b][feat][w]
// ---------------------------------------------------------------------------
__global__ void conv_kernel(const float* __restrict__ x,
                            const float* __restrict__ convT,
                            const float* __restrict__ cb,
                            float* __restrict__ h_catT,
                            float* __restrict__ xconvT)
{
    const int wc = blockIdx.x, b = blockIdx.y, tid = threadIdx.x;
    __shared__ float xs[14][128];
    const int w0 = wc * 8;
#pragma unroll
    for (int i = 0; i < 14; ++i) {
        int row = w0 - 3 + i;
        xs[i][tid] = (row >= 0 && row < 128) ? x[(b * 128 + row) * 128 + tid] : 0.f;
    }
    __syncthreads();
    float bias = cb[tid];
    float acc[8];
#pragma unroll
    for (int j = 0; j < 8; ++j) acc[j] = bias;
    for (int ci = 0; ci < 128; ++ci) {
        float wv[7];
#pragma unroll
        for (int t = 0; t < 7; ++t) wv[t] = convT[(ci * 7 + t) * 128 + tid];
#pragma unroll
        for (int t = 0; t < 7; ++t) {
#pragma unroll
            for (int j = 0; j < 8; ++j) acc[j] += xs[j + t][ci] * wv[t];
        }
    }
#pragma unroll
    for (int j = 0; j < 8; ++j) {
        float v = fmaxf(acc[j], 0.f);
        h_catT[((w0 + j) * 16 + b) * 384 + tid] = v;
        xconvT[(b * 128 + tid) * 128 + w0 + j] = v;
    }
}

// ---------------------------------------------------------------------------
// K2: GATv2 lin projection, factored: P = v@Wl^T + b, Q = v@Wr^T
// ---------------------------------------------------------------------------
__global__ void lin_kernel(const float* __restrict__ vsrc, int mode,
                           const float* __restrict__ T,
                           const float* __restrict__ lb,
                           float* __restrict__ P, float* __restrict__ Q)
{
    const int tid = threadIdx.x;
    const int row0 = blockIdx.x * 8;
    __shared__ __align__(16) float vs[8][128];
    if (mode == 0) {
        ((float4*)vs)[tid] = ((const float4*)(vsrc + row0 * 128))[tid];
    } else {
        int b = row0 >> 7;
        int rr = tid >> 5, q = tid & 31;
        int t = (row0 & 127) + rr;
        *(float4*)&vs[rr][q * 4] = *(const float4*)&vsrc[(t * 16 + b) * 384 + q * 4];
    }
    __syncthreads();
    const int n = tid;
    float bias = lb[n];
    float accP[8], accQ[8];
#pragma unroll
    for (int rr = 0; rr < 8; ++rr) { accP[rr] = bias; accQ[rr] = 0.f; }
    for (int d4 = 0; d4 < 32; ++d4) {
        float4 vv[8];
#pragma unroll
        for (int rr = 0; rr < 8; ++rr) vv[rr] = *(const float4*)&vs[rr][d4 * 4];
#pragma unroll
        for (int e = 0; e < 4; ++e) {
            float wP = T[(d4 * 4 + e) * 256 + n];
            float wQ = T[(128 + d4 * 4 + e) * 256 + n];
#pragma unroll
            for (int rr = 0; rr < 8; ++rr) {
                float h = (e == 0) ? vv[rr].x : (e == 1) ? vv[rr].y : (e == 2) ? vv[rr].z : vv[rr].w;
                accP[rr] += h * wP;
                accQ[rr] += h * wQ;
            }
        }
    }
#pragma unroll
    for (int rr = 0; rr < 8; ++rr) {
        P[(long)(row0 + rr) * 256 + n] = accP[rr];
        Q[(long)(row0 + rr) * 256 + n] = accQ[rr];
    }
}

// ---------------------------------------------------------------------------
// K3: GAT attention. grid 2048 (b,i), block 256.
// ---------------------------------------------------------------------------
__global__ void gat_kernel(const float* __restrict__ P, const float* __restrict__ Q,
                           const float* __restrict__ a,
                           const float* __restrict__ bias,
                           const float* __restrict__ vbase,
                           float* __restrict__ h_catT, int mode)
{
    const int bid = blockIdx.x;
    const int b = bid >> 7, i = bid & 127;
    const int tid = threadIdx.x;
    __shared__ __align__(16) float Ps[256], as_[256], ej[128], red[8], op[256];
    __shared__ __align__(16) float buf[16384];

    Ps[tid]  = P[(long)(b * 128 + i) * 256 + tid];
    as_[tid] = a[tid];

    const int jl = tid >> 3, c = tid & 7;
    for (int j0 = 0; j0 < 128; j0 += 32) {
        __syncthreads();
#pragma unroll
        for (int r = 0; r < 8; ++r) {
            int flat = r * 256 + tid;
            int jj = flat >> 6, e4 = flat & 63;
            *(float4*)&buf[jj * 264 + e4 * 4] =
                *(const float4*)&Q[(long)(b * 128 + j0 + jj) * 256 + e4 * 4];
        }
        __syncthreads();
        float p = 0.f;
        for (int k = 0; k < 32; ++k) {
            int e = c + 8 * k;
            float hv = Ps[e] + buf[jl * 264 + e];
            hv = (hv > 0.f) ? hv : 0.2f * hv;
            p += hv * as_[e];
        }
        p += __shfl_xor(p, 1);
        p += __shfl_xor(p, 2);
        p += __shfl_xor(p, 4);
        if (c == 0) ej[j0 + jl] = p + bias[i * 128 + j0 + jl];
    }
    __syncthreads();
    {   // softmax over 128
        float v = (tid < 128) ? ej[tid] : -1e30f;
#pragma unroll
        for (int off = 32; off >= 1; off >>= 1) v = fmaxf(v, __shfl_xor(v, off));
        if ((tid & 63) == 0) red[tid >> 6] = v;
        __syncthreads();
        float m = fmaxf(fmaxf(red[0], red[1]), fmaxf(red[2], red[3]));
        float p = (tid < 128) ? __expf(ej[tid] - m) : 0.f;
        float s = p;
#pragma unroll
        for (int off = 32; off >= 1; off >>= 1) s += __shfl_xor(s, off);
        if ((tid & 63) == 0) red[4 + (tid >> 6)] = s;
        __syncthreads();
        float rs = fast_rcp(red[4] + red[5] + red[6] + red[7]);
        if (tid < 128) ej[tid] = p * rs;
        __syncthreads();
    }
    if (mode == 0) {
        const float4* s = (const float4*)(vbase + (long)b * 16384);
#pragma unroll
        for (int i2 = 0; i2 < 16; ++i2) ((float4*)buf)[i2 * 256 + tid] = s[i2 * 256 + tid];
    } else {
        int row = tid >> 1, hf = tid & 1;
#pragma unroll
        for (int i2 = 0; i2 < 16; ++i2) {
            int cc = (hf * 16 + i2) * 4;
            *(float4*)&buf[row * 128 + cc] = *(const float4*)&vbase[(row * 16 + b) * 384 + cc];
        }
    }
    __syncthreads();
    const int half = tid >> 7, d = tid & 127;
    float p0 = 0.f, p1 = 0.f, p2 = 0.f, p3 = 0.f;
#pragma unroll 4
    for (int j = 0; j < 64; j += 4) {
        int jb = half * 64 + j;
        p0 += ej[jb]     * buf[(jb)     * 128 + d];
        p1 += ej[jb + 1] * buf[(jb + 1) * 128 + d];
        p2 += ej[jb + 2] * buf[(jb + 2) * 128 + d];
        p3 += ej[jb + 3] * buf[(jb + 3) * 128 + d];
    }
    op[tid] = (p0 + p1) + (p2 + p3);
    __syncthreads();
    if (tid < 128) {
        float o = sigmoidf(op[tid] + op[tid + 128]);
        if (mode == 0)
            h_catT[(tid * 16 + b) * 384 + 128 + i] = o;
        else
            h_catT[(i * 16 + b) * 384 + 256 + tid] = o;
    }
}

// ---------------------------------------------------------------------------
// K4: gi GEMM via MFMA -> giF frag-linear f16. grid 128 (t), block 256.
// ---------------------------------------------------------------------------
__global__ void __launch_bounds__(256)
gi_gemm(const float* __restrict__ h_catT, const f16* __restrict__ w_ihB,
        const float* __restrict__ b_ih, const float* __restrict__ b_hh,
        f16* __restrict__ giF)
{
    const int t = blockIdx.x, tid = threadIdx.x;
    const int w = tid >> 6, lane = tid & 63, quad = lane >> 4, lq = lane & 15;
    __shared__ __align__(16) f16 hA[16][392];
    {
        int rr = tid >> 4, ii = tid & 15;
#pragma unroll
        for (int i2 = 0; i2 < 6; ++i2) {
            int cc = (ii * 6 + i2) * 4;
            float4 v = *(const float4*)&h_catT[(t * 16 + rr) * 384 + cc];
            f16x4 h; h[0] = (f16)v.x; h[1] = (f16)v.y; h[2] = (f16)v.z; h[3] = (f16)v.w;
            *(f16x4*)&hA[rr][cc] = h;
        }
    }
    float biasv[12];
#pragma unroll
    for (int ti = 0; ti < 12; ++ti) {
        int tau = w * 12 + ti, g = tau % 3, jt = tau / 3;
        int n = g * 256 + jt * 16 + lq;
        biasv[ti] = b_ih[n] + (g < 2 ? b_hh[n] : 0.f);
    }
    f32x4 acc[12] = {};
    __syncthreads();
    for (int kk = 0; kk < 12; ++kk) {
        f16x8 A = *(const f16x8*)&hA[lq][kk * 32 + quad * 8];
#pragma unroll
        for (int ti = 0; ti < 12; ++ti) {
            f16x8 B = *(const f16x8*)&w_ihB[(((w * 12 + ti) * 12 + kk) * 64 + lane) * 8];
            acc[ti] = __builtin_amdgcn_mfma_f32_16x16x32_f16(A, B, acc[ti], 0, 0, 0);
        }
    }
#pragma unroll
    for (int ti = 0; ti < 12; ++ti) {
        f16x4 o;
#pragma unroll
        for (int r = 0; r < 4; ++r) o[r] = (f16)(acc[ti][r] + biasv[ti]);
        *(f16x4*)&giF[((t * 48 + w * 12 + ti) * 64 + lane) * 4] = o;
    }
}

// ---------------------------------------------------------------------------
// K4b: decoder-input GEMM via splat-A MFMA. grid 128 (t), block 256.
// ---------------------------------------------------------------------------
__global__ void __launch_bounds__(256)
gi_dec_gemm(const float* __restrict__ h_end, const f16* __restrict__ dwihB,
            const float* __restrict__ dec_b_ih, const float* __restrict__ dec_b_hh,
            f16* __restrict__ giF)
{
    const int t = blockIdx.x, tid = threadIdx.x;
    const int w = tid >> 6, lane = tid & 63, lq = lane & 15;
    float2 e = *(const float2*)&h_end[lq * 256 + 2 * t];
    f16 e0 = (f16)e.x, e1 = (f16)e.y;
    f16x8 A0, A1;
#pragma unroll
    for (int k = 0; k < 8; ++k) { A0[k] = e0; A1[k] = e1; }
    float biasv[12];
#pragma unroll
    for (int ti = 0; ti < 12; ++ti) {
        int tau = w * 12 + ti, g = tau % 3, jt = tau / 3;
        int n = g * 256 + jt * 16 + lq;
        biasv[ti] = dec_b_ih[n] + (g < 2 ? dec_b_hh[n] : 0.f);
    }
    f32x4 acc[12] = {};
    for (int kk = 0; kk < 8; ++kk) {
        f16x8 A = (kk < 4) ? A0 : A1;
#pragma unroll
        for (int ti = 0; ti < 12; ++ti) {
            f16x8 B = *(const f16x8*)&dwihB[(((w * 12 + ti) * 8 + kk) * 64 + lane) * 8];
            acc[ti] = __builtin_amdgcn_mfma_f32_16x16x32_f16(A, B, acc[ti], 0, 0, 0);
        }
    }
#pragma unroll
    for (int ti = 0; ti < 12; ++ti) {
        f16x4 o;
#pragma unroll
        for (int r = 0; r < 4; ++r) o[r] = (f16)(acc[ti][r] + biasv[ti]);
        *(f16x4*)&giF[((t * 48 + w * 12 + ti) * 64 + lane) * 4] = o;
    }
}

// ---------------------------------------------------------------------------
// K5: GRU recurrence via MFMA, 1 block x 1024 thr (16 waves = 4/SIMD).
// Wave w owns jt=w: 3 taus (r,z,n for j in [w*16,(w+1)*16)), Bf = 96 VGPRs ->
// no reg cap, 4 waves/SIMD hide latency (R5 failed at 2 waves/SIMD + cold-HBM
// gv loads INSIDE the step). gv for step t+1 prefetched at top of step t.
// ---------------------------------------------------------------------------
__global__ void __launch_bounds__(1024)
gru_half(const f16* __restrict__ giF, const f16* __restrict__ whhF,
         const float* __restrict__ b_hh_full,
         float* __restrict__ h_end, float* __restrict__ dec_out, int is_dec)
{
    const int tid = threadIdx.x;
    const int w = tid >> 6, lane = tid & 63, quad = lane >> 4, lq = lane & 15;
    __shared__ __align__(16) f16 hA[2][16][264];
    for (int i = tid; i < 2 * 16 * 264; i += 1024) ((f16*)hA)[i] = (f16)0.f;

    f16x8 Bf[3][8];
#pragma unroll
    for (int g = 0; g < 3; ++g)
#pragma unroll
        for (int kk = 0; kk < 8; ++kk)
            Bf[g][kk] = *(const f16x8*)&whhF[(((w * 3 + g) * 8 + kk) * 64 + lane) * 8];
    const float bhn = b_hh_full[512 + w * 16 + lq];
    const int j = w * 16 + lq;
    float hreg[4] = {};
    const f16x4* gp = (const f16x4*)giF;
    f16x4 gv[3];
#pragma unroll
    for (int g = 0; g < 3; ++g) gv[g] = gp[(0 * 48 + w * 3 + g) * 64 + lane];
    __syncthreads();

    for (int t = 0; t < 128; ++t) {
        const int par = t & 1;
        const int tn = (t < 127) ? t + 1 : t;
        f16x4 gnx[3];
#pragma unroll
        for (int g = 0; g < 3; ++g) gnx[g] = gp[(tn * 48 + w * 3 + g) * 64 + lane];
        f32x4 acc[3] = {};
#pragma unroll
        for (int kk = 0; kk < 8; ++kk) {
            f16x8 A = *(const f16x8*)&hA[par][lq][kk * 32 + quad * 8];
#pragma unroll
            for (int g = 0; g < 3; ++g)
                acc[g] = __builtin_amdgcn_mfma_f32_16x16x32_f16(A, Bf[g][kk], acc[g], 0, 0, 0);
        }
#pragma unroll
        for (int r = 0; r < 4; ++r) {
            const int m = quad * 4 + r;
            float gr = sigmoidf((float)gv[0][r] + acc[0][r]);
            float gz = sigmoidf((float)gv[1][r] + acc[1][r]);
            float gn = tanh_f((float)gv[2][r] + gr * (acc[2][r] + bhn));
            float hn = (1.f - gz) * gn + gz * hreg[r];
            hreg[r] = hn;
            hA[par ^ 1][m][j] = (f16)hn;
            if (is_dec) dec_out[(m * 128 + t) * 256 + j] = hn;
        }
#pragma unroll
        for (int g = 0; g < 3; ++g) gv[g] = gnx[g];
        __syncthreads();
    }
    if (!is_dec) {
#pragma unroll
        for (int r = 0; r < 4; ++r)
            h_end[(quad * 4 + r) * 256 + j] = hreg[r];
    }
}

// ---------------------------------------------------------------------------
// K6: forecast MLP. grid 16, block 256.
// ---------------------------------------------------------------------------
__global__ void mlp_kernel(const float* __restrict__ h_end,
                           const float* __restrict__ fc1_w,
                           const float* __restrict__ fc1_b,
                           const float* __restrict__ fc2_w,
                           const float* __restrict__ fc2_b,
                           float* __restrict__ out)
{
    const int b = blockIdx.x, tid = threadIdx.x;
    __shared__ __align__(16) float hv[256], hid[256];
    hv[tid] = h_end[b * 256 + tid];
    __syncthreads();
    float acc = fc1_b[tid], acc2 = 0.f;
    const float4* wr = (const float4*)(fc1_w + tid * 256);
#pragma unroll 4
    for (int i = 0; i < 64; i += 2) {
        float4 w0 = wr[i], w1 = wr[i + 1];
        float4 h0 = *(const float4*)&hv[i * 4], h1 = *(const float4*)&hv[i * 4 + 4];
        acc  += w0.x * h0.x + w0.y * h0.y + w0.z * h0.z + w0.w * h0.w;
        acc2 += w1.x * h1.x + w1.y * h1.y + w1.z * h1.z + w1.w * h1.w;
    }
    hid[tid] = fmaxf(acc + acc2, 0.f);
    __syncthreads();
    if (tid < 128) {
        float a2 = fc2_b[tid], a3 = 0.f;
        const float4* w2 = (const float4*)(fc2_w + tid * 256);
#pragma unroll 4
        for (int i = 0; i < 64; i += 2) {
            float4 w0 = w2[i], w1 = w2[i + 1];
            float4 h0 = *(const float4*)&hid[i * 4], h1 = *(const float4*)&hid[i * 4 + 4];
            a2 += w0.x * h0.x + w0.y * h0.y + w0.z * h0.z + w0.w * h0.w;
            a3 += w1.x * h1.x + w1.y * h1.y + w1.z * h1.z + w1.w * h1.w;
        }
        out[b * 128 + tid] = a2 + a3;
    }
}

// ---------------------------------------------------------------------------
// K7: recons = dec_out @ rec_fc_w^T + b. grid 256 (8 rows), block 256.
// ---------------------------------------------------------------------------
__global__ void recon_kernel(const float* __restrict__ dec_out,
                             const float* __restrict__ recT,
                             const float* __restrict__ rec_b,
                             float* __restrict__ out)
{
    const int blk = blockIdx.x, tid = threadIdx.x;
    __shared__ __align__(16) float dv[8][256];
#pragma unroll
    for (int i = 0; i < 2; ++i)
        ((float4*)dv)[i * 256 + tid] = ((const float4*)(dec_out + blk * 2048))[i * 256 + tid];
    __syncthreads();
    const int j = tid & 127, rh = tid >> 7;
    float acc[4];
#pragma unroll
    for (int rr = 0; rr < 4; ++rr) acc[rr] = rec_b[j];
    for (int d4 = 0; d4 < 64; ++d4) {
        float4 vv[4];
#pragma unroll
        for (int rr = 0; rr < 4; ++rr) vv[rr] = *(const float4*)&dv[rh * 4 + rr][d4 * 4];
#pragma unroll
        for (int e = 0; e < 4; ++e) {
            float wv = recT[(d4 * 4 + e) * 128 + j];
#pragma unroll
            for (int rr = 0; rr < 4; ++rr) {
                float h = (e == 0) ? vv[rr].x : (e == 1) ? vv[rr].y : (e == 2) ? vv[rr].z : vv[rr].w;
                acc[rr] += h * wv;
            }
        }
    }
#pragma unroll
    for (int rr = 0; rr < 4; ++rr)
        out[(blk * 8 + rh * 4 + rr) * 128 + j] = acc[rr];
}

// ---------------------------------------------------------------------------
extern "C" void kernel_launch(void* const* d_in, const int* in_sizes, int n_in,
                              void* d_out, int out_size, void* d_ws, size_t ws_size,
                              hipStream_t stream)
{
    const float* x        = (const float*)d_in[0];
    const float* conv_w   = (const float*)d_in[1];
    const float* conv_b   = (const float*)d_in[2];
    const float* fg_lin_w = (const float*)d_in[3];
    const float* fg_lin_b = (const float*)d_in[4];
    const float* fg_a     = (const float*)d_in[5];
    const float* fg_bias  = (const float*)d_in[6];
    const float* tg_lin_w = (const float*)d_in[7];
    const float* tg_lin_b = (const float*)d_in[8];
    const float* tg_a     = (const float*)d_in[9];
    const float* tg_bias  = (const float*)d_in[10];
    const float* gru_w_ih = (const float*)d_in[11];
    const float* gru_w_hh = (const float*)d_in[12];
    const float* gru_b_ih = (const float*)d_in[13];
    const float* gru_b_hh = (const float*)d_in[14];
    const float* fc1_w    = (const float*)d_in[15];
    const float* fc1_b    = (const float*)d_in[16];
    const float* fc2_w    = (const float*)d_in[17];
    const float* fc2_b    = (const float*)d_in[18];
    const float* dec_w_ih = (const float*)d_in[19];
    const float* dec_w_hh = (const float*)d_in[20];
    const float* dec_b_ih = (const float*)d_in[21];
    const float* dec_b_hh = (const float*)d_in[22];
    const float* rec_fc_w = (const float*)d_in[23];
    const float* rec_fc_b = (const float*)d_in[24];
    float* out = (float*)d_out;

    float* ws      = (float*)d_ws;
    float* h_catT  = ws;
    float* xconvT  = ws + 786432;
    float* Pf      = ws + 1048576;
    float* Qf      = ws + 1572864;
    float* Pt      = ws + 2097152;
    float* Qt      = ws + 2621440;
    f16*   giF     = (f16*)(ws + 3145728);
    f16*   w_ihB   = (f16*)(ws + 3932160);
    f16*   whhE    = (f16*)(ws + 4079616);
    f16*   whhD    = (f16*)(ws + 4177920);
    f16*   dwihB   = (f16*)(ws + 4276224);
    float* linTf   = ws + 4374528;
    float* linTt   = ws + 4440064;
    float* recT    = ws + 4505600;
    float* h_end   = ws + 4538368;
    float* dec_out = ws + 4542464;
    float* convT   = dec_out;   // alias: conv reads before gru_dec writes dec_out

    prep_kernel<<<3392, 64, 0, stream>>>(conv_w, fg_lin_w, tg_lin_w, gru_w_ih, gru_w_hh,
                                         dec_w_ih, dec_w_hh, rec_fc_w,
                                         w_ihB, whhE, whhD, dwihB, linTf, linTt, recT, convT);
    conv_kernel<<<dim3(16, 16), 128, 0, stream>>>(x, convT, conv_b, h_catT, xconvT);
    lin_kernel<<<256, 256, 0, stream>>>(xconvT, 0, linTf, fg_lin_b, Pf, Qf);
    lin_kernel<<<256, 256, 0, stream>>>(h_catT, 1, linTt, tg_lin_b, Pt, Qt);
    gat_kernel<<<2048, 256, 0, stream>>>(Pf, Qf, fg_a, fg_bias, xconvT, h_catT, 0);
    gat_kernel<<<2048, 256, 0, stream>>>(Pt, Qt, tg_a, tg_bias, h_catT, h_catT, 1);
    gi_gemm<<<128, 256, 0, stream>>>(h_catT, w_ihB, gru_b_ih, gru_b_hh, giF);
    gru_half<<<1, 1024, 0, stream>>>(giF, whhE, gru_b_hh, h_end, dec_out, 0);
    gi_dec_gemm<<<128, 256, 0, stream>>>(h_end, dwihB, dec_b_ih, dec_b_hh, giF);
    mlp_kernel<<<16, 256, 0, stream>>>(h_end, fc1_w, fc1_b, fc2_w, fc2_b, out);
    gru_half<<<1, 1024, 0, stream>>>(giF, whhD, dec_b_hh, h_end, dec_out, 1);
    recon_kernel<<<256, 256, 0, stream>>>(dec_out, recT, rec_fc_b, out + 2048);
}

// Round 7
// 718.570 us; speedup vs baseline: 1.6470x; 1.5096x over previous
//
#include <hip/hip_runtime.h>

typedef _Float16 f16;
typedef _Float16 f16x2 __attribute__((ext_vector_type(2)));
typedef _Float16 f16x4 __attribute__((ext_vector_type(4)));
typedef _Float16 f16x8 __attribute__((ext_vector_type(8)));
typedef float f32x4 __attribute__((ext_vector_type(4)));
typedef unsigned int ui4 __attribute__((ext_vector_type(4)));

__device__ __forceinline__ float fast_rcp(float x) {
#if __has_builtin(__builtin_amdgcn_rcpf)
    return __builtin_amdgcn_rcpf(x);
#else
    return 1.0f / x;
#endif
}
__device__ __forceinline__ float sigmoidf(float x) { return fast_rcp(1.0f + __expf(-x)); }
__device__ __forceinline__ float tanh_f(float x)   { return 2.0f * fast_rcp(1.0f + __expf(-2.0f * x)) - 1.0f; }

__device__ __forceinline__ unsigned int pk2(float a, float b) {
    union { _Float16 h[2]; unsigned int u; } t;
    t.h[0] = (_Float16)a; t.h[1] = (_Float16)b;
    return t.u;
}
__device__ __forceinline__ unsigned short f16bits(float f) {
    union { _Float16 h; unsigned short u; } t; t.h = (_Float16)f; return t.u;
}
__device__ __forceinline__ float dot2f(unsigned int wa, unsigned int hb, float c) {
#if __has_builtin(__builtin_amdgcn_fdot2)
    return __builtin_amdgcn_fdot2(__builtin_bit_cast(f16x2, wa),
                                  __builtin_bit_cast(f16x2, hb), c, false);
#else
    f16x2 a = __builtin_bit_cast(f16x2, wa), b = __builtin_bit_cast(f16x2, hb);
    return c + (float)a.x * (float)b.x + (float)a.y * (float)b.y;
#endif
}

// ===========================================================================
// ws layout (f32 units):
//  h_catT  0        786432   [t][b][384]
//  xconvT  786432   262144   [b][feat][w]
//  Pf      1048576  524288   } gi (f32 [b][t][768], 1572864) ALIASES Pf+Qf+Pt
//  Qf      1572864  524288   }   (written by gi_gemm32 after gat consumed P/Q)
//  Pt      2097152  524288   }
//  Qt      2621440  524288
//  (spare) 3145728
//  w_ihB   3932160  73728    f16 frags [tau48][kk12][lane][8]
//  wpkE    4079616  98304    u32 packed-f16 pairs [g][i64][tid512]
//  wpkD    4177920  98304
//  c01     4276224  1536     decoder column-half sums [2][768]
//  linTf   4374528  65536
//  linTt   4440064  65536
//  recT    4505600  32768
//  h_end   4538368  4096
//  dec_out 4542464  524288   (aliased as convT early: conv reads before gru writes)
// ===========================================================================

// ---------------------------------------------------------------------------
// K0: prep — weight transposes, MFMA frags, packed GRU weights (one-time)
// grid 2636 x 64
// ---------------------------------------------------------------------------
__global__ void prep_kernel(const float* __restrict__ conv_w,
                            const float* __restrict__ fg_lin_w,
                            const float* __restrict__ tg_lin_w,
                            const float* __restrict__ w_ih,
                            const float* __restrict__ w_hh,
                            const float* __restrict__ dec_w_ih,
                            const float* __restrict__ dec_w_hh,
                            const float* __restrict__ rec_fc_w,
                            f16* __restrict__ w_ihB,
                            unsigned int* __restrict__ wpkE,
                            unsigned int* __restrict__ wpkD,
                            float* __restrict__ c01,
                            float* __restrict__ linTf, float* __restrict__ linTt,
                            float* __restrict__ recT, float* __restrict__ convT)
{
    const int blk = blockIdx.x, lane = threadIdx.x;
    const int quad = lane >> 4, lq = lane & 15;
    if (blk < 576) {                       // w_ihB (K=384) MFMA B-frags
        int tau = blk / 12, kk = blk % 12;
        int g = tau % 3, jt = tau / 3;
        int n = g * 256 + jt * 16 + lq;
        int k0 = kk * 32 + quad * 8;
        f16x8 v;
#pragma unroll
        for (int e = 0; e < 8; ++e) v[e] = (f16)w_ih[n * 384 + k0 + e];
        *(f16x8*)&w_ihB[(blk * 64 + lane) * 8] = v;
    } else if (blk < 960) {                // wpkE / wpkD: packed fp16 pairs
        int i2 = blk - 576;
        const float* src = w_hh; unsigned int* dst = wpkE;
        if (i2 >= 192) { i2 -= 192; src = dec_w_hh; dst = wpkD; }
        int g = i2 >> 6, i = i2 & 63;
#pragma unroll
        for (int c = 0; c < 8; ++c) {
            int tidx = lane * 8 + c;
            int j = tidx >> 1, half = tidx & 1;
            int n = g * 256 + j, k = half * 128 + i * 2;
            dst[(g * 64 + i) * 512 + tidx] = pk2(src[n * 256 + k], src[n * 256 + k + 1]);
        }
    } else if (blk < 972) {                // c01 decoder column-half sums
        int n = (blk - 960) * 64 + lane;
        float s0 = 0.f, s1 = 0.f;
        const float* row = dec_w_ih + (long)n * 256;
        for (int d = 0; d < 128; ++d) { s0 += row[d]; s1 += row[128 + d]; }
        c01[n] = s0; c01[768 + n] = s1;
    } else if (blk < 1484) {               // lin transposes
        int i = blk - 972; int mat = i >> 8, d = i & 255;
        const float* src = mat ? tg_lin_w : fg_lin_w;
        float* dst = mat ? linTt : linTf;
#pragma unroll
        for (int c = 0; c < 4; ++c) { int n = lane + 64 * c; dst[d * 256 + n] = src[n * 256 + d]; }
    } else if (blk < 1740) {               // recT
        int d = blk - 1484;
#pragma unroll
        for (int c = 0; c < 2; ++c) { int j2 = lane + 64 * c; recT[d * 128 + j2] = rec_fc_w[j2 * 256 + d]; }
    } else {                               // convT, blk < 2636
        int i = blk - 1740;
#pragma unroll
        for (int c = 0; c < 2; ++c) { int co = lane + 64 * c; convT[i * 128 + co] = conv_w[co * 896 + i]; }
    }
}

// ---------------------------------------------------------------------------
// K1: Conv1d (KS=7, pad 3) + ReLU -> h_catT[t][b][0:128] and xconvT[b][feat][w]
// ---------------------------------------------------------------------------
__global__ void conv_kernel(const float* __restrict__ x,
                            const float* __restrict__ convT,
                            const float* __restrict__ cb,
                            float* __restrict__ h_catT,
                            float* __restrict__ xconvT)
{
    const int wc = blockIdx.x, b = blockIdx.y, tid = threadIdx.x;
    __shared__ float xs[14][128];
    const int w0 = wc * 8;
#pragma unroll
    for (int i = 0; i < 14; ++i) {
        int row = w0 - 3 + i;
        xs[i][tid] = (row >= 0 && row < 128) ? x[(b * 128 + row) * 128 + tid] : 0.f;
    }
    __syncthreads();
    float bias = cb[tid];
    float acc[8];
#pragma unroll
    for (int j = 0; j < 8; ++j) acc[j] = bias;
    for (int ci = 0; ci < 128; ++ci) {
        float wv[7];
#pragma unroll
        for (int t = 0; t < 7; ++t) wv[t] = convT[(ci * 7 + t) * 128 + tid];
#pragma unroll
        for (int t = 0; t < 7; ++t) {
#pragma unroll
            for (int j = 0; j < 8; ++j) acc[j] += xs[j + t][ci] * wv[t];
        }
    }
#pragma unroll
    for (int j = 0; j < 8; ++j) {
        float v = fmaxf(acc[j], 0.f);
        h_catT[((w0 + j) * 16 + b) * 384 + tid] = v;
        xconvT[(b * 128 + tid) * 128 + w0 + j] = v;
    }
}

// ---------------------------------------------------------------------------
// K2: GATv2 lin projection, factored: P = v@Wl^T + b, Q = v@Wr^T
// ---------------------------------------------------------------------------
__global__ void lin_kernel(const float* __restrict__ vsrc, int mode,
                           const float* __restrict__ T,
                           const float* __restrict__ lb,
                           float* __restrict__ P, float* __restrict__ Q)
{
    const int tid = threadIdx.x;
    const int row0 = blockIdx.x * 8;
    __shared__ __align__(16) float vs[8][128];
    if (mode == 0) {
        ((float4*)vs)[tid] = ((const float4*)(vsrc + row0 * 128))[tid];
    } else {
        int b = row0 >> 7;
        int rr = tid >> 5, q = tid & 31;
        int t = (row0 & 127) + rr;
        *(float4*)&vs[rr][q * 4] = *(const float4*)&vsrc[(t * 16 + b) * 384 + q * 4];
    }
    __syncthreads();
    const int n = tid;
    float bias = lb[n];
    float accP[8], accQ[8];
#pragma unroll
    for (int rr = 0; rr < 8; ++rr) { accP[rr] = bias; accQ[rr] = 0.f; }
    for (int d4 = 0; d4 < 32; ++d4) {
        float4 vv[8];
#pragma unroll
        for (int rr = 0; rr < 8; ++rr) vv[rr] = *(const float4*)&vs[rr][d4 * 4];
#pragma unroll
        for (int e = 0; e < 4; ++e) {
            float wP = T[(d4 * 4 + e) * 256 + n];
            float wQ = T[(128 + d4 * 4 + e) * 256 + n];
#pragma unroll
            for (int rr = 0; rr < 8; ++rr) {
                float h = (e == 0) ? vv[rr].x : (e == 1) ? vv[rr].y : (e == 2) ? vv[rr].z : vv[rr].w;
                accP[rr] += h * wP;
                accQ[rr] += h * wQ;
            }
        }
    }
#pragma unroll
    for (int rr = 0; rr < 8; ++rr) {
        P[(long)(row0 + rr) * 256 + n] = accP[rr];
        Q[(long)(row0 + rr) * 256 + n] = accQ[rr];
    }
}

// ---------------------------------------------------------------------------
// K3: GAT attention. grid 2048 (b,i), block 256.
// ---------------------------------------------------------------------------
__global__ void gat_kernel(const float* __restrict__ P, const float* __restrict__ Q,
                           const float* __restrict__ a,
                           const float* __restrict__ bias,
                           const float* __restrict__ vbase,
                           float* __restrict__ h_catT, int mode)
{
    const int bid = blockIdx.x;
    const int b = bid >> 7, i = bid & 127;
    const int tid = threadIdx.x;
    __shared__ __align__(16) float Ps[256], as_[256], ej[128], red[8], op[256];
    __shared__ __align__(16) float buf[16384];

    Ps[tid]  = P[(long)(b * 128 + i) * 256 + tid];
    as_[tid] = a[tid];

    const int jl = tid >> 3, c = tid & 7;
    for (int j0 = 0; j0 < 128; j0 += 32) {
        __syncthreads();
#pragma unroll
        for (int r = 0; r < 8; ++r) {
            int flat = r * 256 + tid;
            int jj = flat >> 6, e4 = flat & 63;
            *(float4*)&buf[jj * 264 + e4 * 4] =
                *(const float4*)&Q[(long)(b * 128 + j0 + jj) * 256 + e4 * 4];
        }
        __syncthreads();
        float p = 0.f;
        for (int k = 0; k < 32; ++k) {
            int e = c + 8 * k;
            float hv = Ps[e] + buf[jl * 264 + e];
            hv = (hv > 0.f) ? hv : 0.2f * hv;
            p += hv * as_[e];
        }
        p += __shfl_xor(p, 1);
        p += __shfl_xor(p, 2);
        p += __shfl_xor(p, 4);
        if (c == 0) ej[j0 + jl] = p + bias[i * 128 + j0 + jl];
    }
    __syncthreads();
    {   // softmax over 128
        float v = (tid < 128) ? ej[tid] : -1e30f;
#pragma unroll
        for (int off = 32; off >= 1; off >>= 1) v = fmaxf(v, __shfl_xor(v, off));
        if ((tid & 63) == 0) red[tid >> 6] = v;
        __syncthreads();
        float m = fmaxf(fmaxf(red[0], red[1]), fmaxf(red[2], red[3]));
        float p = (tid < 128) ? __expf(ej[tid] - m) : 0.f;
        float s = p;
#pragma unroll
        for (int off = 32; off >= 1; off >>= 1) s += __shfl_xor(s, off);
        if ((tid & 63) == 0) red[4 + (tid >> 6)] = s;
        __syncthreads();
        float rs = fast_rcp(red[4] + red[5] + red[6] + red[7]);
        if (tid < 128) ej[tid] = p * rs;
        __syncthreads();
    }
    if (mode == 0) {
        const float4* s = (const float4*)(vbase + (long)b * 16384);
#pragma unroll
        for (int i2 = 0; i2 < 16; ++i2) ((float4*)buf)[i2 * 256 + tid] = s[i2 * 256 + tid];
    } else {
        int row = tid >> 1, hf = tid & 1;
#pragma unroll
        for (int i2 = 0; i2 < 16; ++i2) {
            int cc = (hf * 16 + i2) * 4;
            *(float4*)&buf[row * 128 + cc] = *(const float4*)&vbase[(row * 16 + b) * 384 + cc];
        }
    }
    __syncthreads();
    const int half = tid >> 7, d = tid & 127;
    float p0 = 0.f, p1 = 0.f, p2 = 0.f, p3 = 0.f;
#pragma unroll 4
    for (int j = 0; j < 64; j += 4) {
        int jb = half * 64 + j;
        p0 += ej[jb]     * buf[(jb)     * 128 + d];
        p1 += ej[jb + 1] * buf[(jb + 1) * 128 + d];
        p2 += ej[jb + 2] * buf[(jb + 2) * 128 + d];
        p3 += ej[jb + 3] * buf[(jb + 3) * 128 + d];
    }
    op[tid] = (p0 + p1) + (p2 + p3);
    __syncthreads();
    if (tid < 128) {
        float o = sigmoidf(op[tid] + op[tid + 128]);
        if (mode == 0)
            h_catT[(tid * 16 + b) * 384 + 128 + i] = o;
        else
            h_catT[(i * 16 + b) * 384 + 256 + tid] = o;
    }
}

// ---------------------------------------------------------------------------
// K4: gi GEMM via MFMA -> f32 gi[b][t][768] (= h_cat@w_ih^T + b_ih).
// grid 128 (t), block 256. b_hh is added inside the GRU.
// ---------------------------------------------------------------------------
__global__ void __launch_bounds__(256)
gi_gemm32(const float* __restrict__ h_catT, const f16* __restrict__ w_ihB,
          const float* __restrict__ b_ih, float* __restrict__ gi)
{
    const int t = blockIdx.x, tid = threadIdx.x;
    const int w = tid >> 6, lane = tid & 63, quad = lane >> 4, lq = lane & 15;
    __shared__ __align__(16) f16 hA[16][392];
    {
        int rr = tid >> 4, ii = tid & 15;
#pragma unroll
        for (int i2 = 0; i2 < 6; ++i2) {
            int cc = (ii * 6 + i2) * 4;
            float4 v = *(const float4*)&h_catT[(t * 16 + rr) * 384 + cc];
            f16x4 h; h[0] = (f16)v.x; h[1] = (f16)v.y; h[2] = (f16)v.z; h[3] = (f16)v.w;
            *(f16x4*)&hA[rr][cc] = h;
        }
    }
    int nidx[12];
    float biasv[12];
#pragma unroll
    for (int ti = 0; ti < 12; ++ti) {
        int tau = w * 12 + ti, g = tau % 3, jt = tau / 3;
        nidx[ti] = g * 256 + jt * 16 + lq;
        biasv[ti] = b_ih[nidx[ti]];
    }
    f32x4 acc[12] = {};
    __syncthreads();
    for (int kk = 0; kk < 12; ++kk) {
        f16x8 A = *(const f16x8*)&hA[lq][kk * 32 + quad * 8];
#pragma unroll
        for (int ti = 0; ti < 12; ++ti) {
            f16x8 B = *(const f16x8*)&w_ihB[(((w * 12 + ti) * 12 + kk) * 64 + lane) * 8];
            acc[ti] = __builtin_amdgcn_mfma_f32_16x16x32_f16(A, B, acc[ti], 0, 0, 0);
        }
    }
#pragma unroll
    for (int ti = 0; ti < 12; ++ti)
#pragma unroll
        for (int r = 0; r < 4; ++r) {
            int m = quad * 4 + r;
            gi[((long)m * 128 + t) * 768 + nidx[ti]] = acc[ti][r] + biasv[ti];
        }
}

// ---------------------------------------------------------------------------
// K5: both GRUs, batch-split across 16 blocks (R4 structure, proven 395us).
// 512 thr: thread = (j = tid>>1, half = tid&1); w_hh as packed fp16 pairs in
// 192 regs, loaded COALESCED from prep's wpk[g][i][tid]. gi staged to LDS in
// 32-step chunks; dec_out buffered in LDS, flushed per chunk. Decoder input
// via precomputed C0/C1 column sums (c01).
// ---------------------------------------------------------------------------
__global__ void __launch_bounds__(512, 2)
gru16_kernel(const float* __restrict__ gi,
             const unsigned int* __restrict__ wpkE,
             const float* __restrict__ b_hh,
             const float* __restrict__ c01,
             const float* __restrict__ dec_b_ih,
             const unsigned int* __restrict__ wpkD,
             const float* __restrict__ dec_b_hh,
             float* __restrict__ h_end,
             float* __restrict__ dec_out)
{
    const int b    = blockIdx.x;
    const int tid  = threadIdx.x;
    const int j    = tid >> 1;
    const int half = tid & 1;

    __shared__ __align__(16) unsigned short hpk[2][256];
    __shared__ float he[256];
    __shared__ __align__(16) float gich[32 * 768];   // 96KB; decoder reuses

    unsigned int wr[3][64];
    float bh[3];
#pragma unroll
    for (int g = 0; g < 3; ++g) {
        bh[g] = b_hh[g * 256 + j];
#pragma unroll
        for (int i = 0; i < 64; ++i) wr[g][i] = wpkE[(g * 64 + i) * 512 + tid];
    }
    if (tid < 256) { hpk[0][tid] = 0; hpk[1][tid] = 0; }
    float h = 0.f;

    const float* gib = gi + (long)b * 128 * 768;
    const unsigned int* hbase0 = ((const unsigned int*)hpk[0]) + half * 64;
    const unsigned int* hbase1 = ((const unsigned int*)hpk[1]) + half * 64;

    // ======== encoder: 4 chunks x 32 steps ========
    for (int cchunk = 0; cchunk < 4; ++cchunk) {
        const float* gsrc = gib + (long)cchunk * 32 * 768;
#pragma unroll
        for (int i = 0; i < 12; ++i) {
            int idx = (i * 512 + tid) * 4;
            *(float4*)&gich[idx] = *(const float4*)&gsrc[idx];
        }
        __syncthreads();
        for (int tt = 0; tt < 32; ++tt) {
            const int t = cchunk * 32 + tt;
            const int par = t & 1;
            float g0 = gich[tt * 768 + j];
            float g1 = gich[tt * 768 + 256 + j];
            float g2 = gich[tt * 768 + 512 + j];
            float aa0[4] = {}, aa1[4] = {}, aa2[4] = {};
            const ui4* hp = (const ui4*)(par ? hbase1 : hbase0);
#pragma unroll
            for (int i = 0; i < 16; ++i) {
                ui4 hv = hp[i];
#pragma unroll
                for (int e = 0; e < 4; ++e) {
                    aa0[e] = dot2f(wr[0][i * 4 + e], hv[e], aa0[e]);
                    aa1[e] = dot2f(wr[1][i * 4 + e], hv[e], aa1[e]);
                    aa2[e] = dot2f(wr[2][i * 4 + e], hv[e], aa2[e]);
                }
            }
            float a0 = (aa0[0] + aa0[1]) + (aa0[2] + aa0[3]);
            float a1 = (aa1[0] + aa1[1]) + (aa1[2] + aa1[3]);
            float a2 = (aa2[0] + aa2[1]) + (aa2[2] + aa2[3]);
            a0 += __shfl_xor(a0, 1);
            a1 += __shfl_xor(a1, 1);
            a2 += __shfl_xor(a2, 1);
            float rr = sigmoidf(g0 + a0 + bh[0]);
            float zz = sigmoidf(g1 + a1 + bh[1]);
            float nn = tanh_f  (g2 + rr * (a2 + bh[2]));
            h = (1.f - zz) * nn + zz * h;
            if (!half) hpk[par ^ 1][j] = f16bits(h);
            __syncthreads();
        }
    }

    // ---- h_end, switch to decoder ----
    if (!half) { he[j] = h; h_end[b * 256 + j] = h; }
    if (tid < 256) { hpk[0][tid] = 0; hpk[1][tid] = 0; }

    float c0[3], c1[3], bi[3];
#pragma unroll
    for (int g = 0; g < 3; ++g) {
        bh[g] = dec_b_hh[g * 256 + j];
        bi[g] = dec_b_ih[g * 256 + j];
        c0[g] = c01[g * 256 + j];
        c1[g] = c01[768 + g * 256 + j];
#pragma unroll
        for (int i = 0; i < 64; ++i) wr[g][i] = wpkD[(g * 64 + i) * 512 + tid];
    }
    h = 0.f;
    float* decbuf = gich;
    __syncthreads();

    // ======== decoder: 4 chunks x 32 steps ========
    for (int cchunk = 0; cchunk < 4; ++cchunk) {
        for (int tt = 0; tt < 32; ++tt) {
            const int t = cchunk * 32 + tt;
            const int par = t & 1;
            float e0 = he[2 * t], e1 = he[2 * t + 1];
            float aa0[4] = {}, aa1[4] = {}, aa2[4] = {};
            const ui4* hp = (const ui4*)(par ? hbase1 : hbase0);
#pragma unroll
            for (int i = 0; i < 16; ++i) {
                ui4 hv = hp[i];
#pragma unroll
                for (int e = 0; e < 4; ++e) {
                    aa0[e] = dot2f(wr[0][i * 4 + e], hv[e], aa0[e]);
                    aa1[e] = dot2f(wr[1][i * 4 + e], hv[e], aa1[e]);
                    aa2[e] = dot2f(wr[2][i * 4 + e], hv[e], aa2[e]);
                }
            }
            float a0 = (aa0[0] + aa0[1]) + (aa0[2] + aa0[3]);
            float a1 = (aa1[0] + aa1[1]) + (aa1[2] + aa1[3]);
            float a2 = (aa2[0] + aa2[1]) + (aa2[2] + aa2[3]);
            a0 += __shfl_xor(a0, 1);
            a1 += __shfl_xor(a1, 1);
            a2 += __shfl_xor(a2, 1);
            float rr = sigmoidf(e0 * c0[0] + e1 * c1[0] + bi[0] + a0 + bh[0]);
            float zz = sigmoidf(e0 * c0[1] + e1 * c1[1] + bi[1] + a1 + bh[1]);
            float nn = tanh_f  (e0 * c0[2] + e1 * c1[2] + bi[2] + rr * (a2 + bh[2]));
            h = (1.f - zz) * nn + zz * h;
            if (!half) {
                hpk[par ^ 1][j] = f16bits(h);
                decbuf[tt * 256 + j] = h;
            }
            __syncthreads();
        }
#pragma unroll
        for (int i = 0; i < 4; ++i) {
            int idx = (i * 512 + tid) * 4;
            *(float4*)&dec_out[(long)b * 32768 + cchunk * 8192 + idx] = *(const float4*)&decbuf[idx];
        }
        __syncthreads();
    }
}

// ---------------------------------------------------------------------------
// K6: forecast MLP. grid 16, block 256.
// ---------------------------------------------------------------------------
__global__ void mlp_kernel(const float* __restrict__ h_end,
                           const float* __restrict__ fc1_w,
                           const float* __restrict__ fc1_b,
                           const float* __restrict__ fc2_w,
                           const float* __restrict__ fc2_b,
                           float* __restrict__ out)
{
    const int b = blockIdx.x, tid = threadIdx.x;
    __shared__ __align__(16) float hv[256], hid[256];
    hv[tid] = h_end[b * 256 + tid];
    __syncthreads();
    float acc = fc1_b[tid], acc2 = 0.f;
    const float4* wr = (const float4*)(fc1_w + tid * 256);
#pragma unroll 4
    for (int i = 0; i < 64; i += 2) {
        float4 w0 = wr[i], w1 = wr[i + 1];
        float4 h0 = *(const float4*)&hv[i * 4], h1 = *(const float4*)&hv[i * 4 + 4];
        acc  += w0.x * h0.x + w0.y * h0.y + w0.z * h0.z + w0.w * h0.w;
        acc2 += w1.x * h1.x + w1.y * h1.y + w1.z * h1.z + w1.w * h1.w;
    }
    hid[tid] = fmaxf(acc + acc2, 0.f);
    __syncthreads();
    if (tid < 128) {
        float a2 = fc2_b[tid], a3 = 0.f;
        const float4* w2 = (const float4*)(fc2_w + tid * 256);
#pragma unroll 4
        for (int i = 0; i < 64; i += 2) {
            float4 w0 = w2[i], w1 = w2[i + 1];
            float4 h0 = *(const float4*)&hid[i * 4], h1 = *(const float4*)&hid[i * 4 + 4];
            a2 += w0.x * h0.x + w0.y * h0.y + w0.z * h0.z + w0.w * h0.w;
            a3 += w1.x * h1.x + w1.y * h1.y + w1.z * h1.z + w1.w * h1.w;
        }
        out[b * 128 + tid] = a2 + a3;
    }
}

// ---------------------------------------------------------------------------
// K7: recons = dec_out @ rec_fc_w^T + b. grid 256 (8 rows), block 256.
// ---------------------------------------------------------------------------
__global__ void recon_kernel(const float* __restrict__ dec_out,
                             const float* __restrict__ recT,
                             const float* __restrict__ rec_b,
                             float* __restrict__ out)
{
    const int blk = blockIdx.x, tid = threadIdx.x;
    __shared__ __align__(16) float dv[8][256];
#pragma unroll
    for (int i = 0; i < 2; ++i)
        ((float4*)dv)[i * 256 + tid] = ((const float4*)(dec_out + blk * 2048))[i * 256 + tid];
    __syncthreads();
    const int j = tid & 127, rh = tid >> 7;
    float acc[4];
#pragma unroll
    for (int rr = 0; rr < 4; ++rr) acc[rr] = rec_b[j];
    for (int d4 = 0; d4 < 64; ++d4) {
        float4 vv[4];
#pragma unroll
        for (int rr = 0; rr < 4; ++rr) vv[rr] = *(const float4*)&dv[rh * 4 + rr][d4 * 4];
#pragma unroll
        for (int e = 0; e < 4; ++e) {
            float wv = recT[(d4 * 4 + e) * 128 + j];
#pragma unroll
            for (int rr = 0; rr < 4; ++rr) {
                float h = (e == 0) ? vv[rr].x : (e == 1) ? vv[rr].y : (e == 2) ? vv[rr].z : vv[rr].w;
                acc[rr] += h * wv;
            }
        }
    }
#pragma unroll
    for (int rr = 0; rr < 4; ++rr)
        out[(blk * 8 + rh * 4 + rr) * 128 + j] = acc[rr];
}

// ---------------------------------------------------------------------------
extern "C" void kernel_launch(void* const* d_in, const int* in_sizes, int n_in,
                              void* d_out, int out_size, void* d_ws, size_t ws_size,
                              hipStream_t stream)
{
    const float* x        = (const float*)d_in[0];
    const float* conv_w   = (const float*)d_in[1];
    const float* conv_b   = (const float*)d_in[2];
    const float* fg_lin_w = (const float*)d_in[3];
    const float* fg_lin_b = (const float*)d_in[4];
    const float* fg_a     = (const float*)d_in[5];
    const float* fg_bias  = (const float*)d_in[6];
    const float* tg_lin_w = (const float*)d_in[7];
    const float* tg_lin_b = (const float*)d_in[8];
    const float* tg_a     = (const float*)d_in[9];
    const float* tg_bias  = (const float*)d_in[10];
    const float* gru_w_ih = (const float*)d_in[11];
    const float* gru_w_hh = (const float*)d_in[12];
    const float* gru_b_ih = (const float*)d_in[13];
    const float* gru_b_hh = (const float*)d_in[14];
    const float* fc1_w    = (const float*)d_in[15];
    const float* fc1_b    = (const float*)d_in[16];
    const float* fc2_w    = (const float*)d_in[17];
    const float* fc2_b    = (const float*)d_in[18];
    const float* dec_w_ih = (const float*)d_in[19];
    const float* dec_w_hh = (const float*)d_in[20];
    const float* dec_b_ih = (const float*)d_in[21];
    const float* dec_b_hh = (const float*)d_in[22];
    const float* rec_fc_w = (const float*)d_in[23];
    const float* rec_fc_b = (const float*)d_in[24];
    float* out = (float*)d_out;

    float* ws      = (float*)d_ws;
    float* h_catT  = ws;
    float* xconvT  = ws + 786432;
    float* Pf      = ws + 1048576;
    float* Qf      = ws + 1572864;
    float* Pt      = ws + 2097152;
    float* Qt      = ws + 2621440;
    float* gi      = Pf;                       // alias: gi_gemm32 runs after gat
    f16*   w_ihB   = (f16*)(ws + 3932160);
    unsigned int* wpkE = (unsigned int*)(ws + 4079616);
    unsigned int* wpkD = (unsigned int*)(ws + 4177920);
    float* c01     = ws + 4276224;
    float* linTf   = ws + 4374528;
    float* linTt   = ws + 4440064;
    float* recT    = ws + 4505600;
    float* h_end   = ws + 4538368;
    float* dec_out = ws + 4542464;
    float* convT   = dec_out;   // alias: conv reads before gru writes dec_out

    prep_kernel<<<2636, 64, 0, stream>>>(conv_w, fg_lin_w, tg_lin_w, gru_w_ih, gru_w_hh,
                                         dec_w_ih, dec_w_hh, rec_fc_w,
                                         w_ihB, wpkE, wpkD, c01, linTf, linTt, recT, convT);
    conv_kernel<<<dim3(16, 16), 128, 0, stream>>>(x, convT, conv_b, h_catT, xconvT);
    lin_kernel<<<256, 256, 0, stream>>>(xconvT, 0, linTf, fg_lin_b, Pf, Qf);
    lin_kernel<<<256, 256, 0, stream>>>(h_catT, 1, linTt, tg_lin_b, Pt, Qt);
    gat_kernel<<<2048, 256, 0, stream>>>(Pf, Qf, fg_a, fg_bias, xconvT, h_catT, 0);
    gat_kernel<<<2048, 256, 0, stream>>>(Pt, Qt, tg_a, tg_bias, h_catT, h_catT, 1);
    gi_gemm32<<<128, 256, 0, stream>>>(h_catT, w_ihB, gru_b_ih, gi);
    gru16_kernel<<<16, 512, 0, stream>>>(gi, wpkE, gru_b_hh, c01, dec_b_ih, wpkD,
                                         dec_b_hh, h_end, dec_out);
    mlp_kernel<<<16, 256, 0, stream>>>(h_end, fc1_w, fc1_b, fc2_w, fc2_b, out);
    recon_kernel<<<256, 256, 0, stream>>>(dec_out, recT, rec_fc_b, out + 2048);
}

// Round 9
// 707.880 us; speedup vs baseline: 1.6718x; 1.0151x over previous
//
#include <hip/hip_runtime.h>

typedef _Float16 f16;
typedef _Float16 f16x2 __attribute__((ext_vector_type(2)));
typedef _Float16 f16x4 __attribute__((ext_vector_type(4)));
typedef _Float16 f16x8 __attribute__((ext_vector_type(8)));
typedef float f32x4 __attribute__((ext_vector_type(4)));
typedef unsigned int ui4 __attribute__((ext_vector_type(4)));

__device__ __forceinline__ float fast_rcp(float x) {
#if __has_builtin(__builtin_amdgcn_rcpf)
    return __builtin_amdgcn_rcpf(x);
#else
    return 1.0f / x;
#endif
}
__device__ __forceinline__ float sigmoidf(float x) { return fast_rcp(1.0f + __expf(-x)); }
__device__ __forceinline__ float tanh_f(float x)   { return 2.0f * fast_rcp(1.0f + __expf(-2.0f * x)) - 1.0f; }

__device__ __forceinline__ unsigned int pk2(float a, float b) {
    union { _Float16 h[2]; unsigned int u; } t;
    t.h[0] = (_Float16)a; t.h[1] = (_Float16)b;
    return t.u;
}
__device__ __forceinline__ unsigned short f16bits(float f) {
    union { _Float16 h; unsigned short u; } t; t.h = (_Float16)f; return t.u;
}
__device__ __forceinline__ float dot2f(unsigned int wa, unsigned int hb, float c) {
#if __has_builtin(__builtin_amdgcn_fdot2)
    return __builtin_amdgcn_fdot2(__builtin_bit_cast(f16x2, wa),
                                  __builtin_bit_cast(f16x2, hb), c, false);
#else
    f16x2 a = __builtin_bit_cast(f16x2, wa), b = __builtin_bit_cast(f16x2, hb);
    return c + (float)a.x * (float)b.x + (float)a.y * (float)b.y;
#endif
}
// quad reduction via DPP (VALU pipe, zero LDS). Lanes 4k..4k+3 form the quad.
__device__ __forceinline__ float quad_reduce(float x) {
#if __has_builtin(__builtin_amdgcn_mov_dpp)
    int a = __builtin_amdgcn_mov_dpp(__builtin_bit_cast(int, x), 0xB1, 0xF, 0xF, true);
    x += __builtin_bit_cast(float, a);
    int b = __builtin_amdgcn_mov_dpp(__builtin_bit_cast(int, x), 0x4E, 0xF, 0xF, true);
    x += __builtin_bit_cast(float, b);
    return x;
#else
    x += __shfl_xor(x, 1);
    x += __shfl_xor(x, 2);
    return x;
#endif
}

// ===========================================================================
// ws layout (f32 units):
//  h_catT  0        786432   [t][b][384]
//  xconvT  786432   262144   [b][feat][w]
//  Pf      1048576  524288   } gi (f32 [b][t][768]) ALIASES Pf+Qf+Pt
//  Qf      1572864  524288   }
//  Pt      2097152  524288   }
//  Qt      2621440  524288
//  w_ihB   3932160  73728    f16 frags [tau48][kk12][lane][8]
//  wpkE    4079616  98304    u32 packed-f16 pairs [r6][i32][tid512]
//  wpkD    4177920  98304
//  c01     4276224  1536     decoder column-half sums [2][768]
//  linTf   4374528  65536
//  linTt   4440064  65536
//  recT    4505600  32768
//  h_end   4538368  4096
//  dec_out 4542464  524288   (aliased as convT early)
// GRU thread map: tid = jt*4+q (jt 0..127, q 0..3). Row r = g*2+jh:
//   n_r = (r>>1)*256 + (r&1)*128 + jt ; k-range = [q*64, q*64+64)
// ===========================================================================

// ---------------------------------------------------------------------------
// K0: prep — weight transposes, MFMA frags, packed GRU weights (one-time)
// grid 2636 x 64
// ---------------------------------------------------------------------------
__global__ void prep_kernel(const float* __restrict__ conv_w,
                            const float* __restrict__ fg_lin_w,
                            const float* __restrict__ tg_lin_w,
                            const float* __restrict__ w_ih,
                            const float* __restrict__ w_hh,
                            const float* __restrict__ dec_w_ih,
                            const float* __restrict__ dec_w_hh,
                            const float* __restrict__ rec_fc_w,
                            f16* __restrict__ w_ihB,
                            unsigned int* __restrict__ wpkE,
                            unsigned int* __restrict__ wpkD,
                            float* __restrict__ c01,
                            float* __restrict__ linTf, float* __restrict__ linTt,
                            float* __restrict__ recT, float* __restrict__ convT)
{
    const int blk = blockIdx.x, lane = threadIdx.x;
    const int quad = lane >> 4, lq = lane & 15;
    if (blk < 576) {                       // w_ihB (K=384) MFMA B-frags
        int tau = blk / 12, kk = blk % 12;
        int g = tau % 3, jt = tau / 3;
        int n = g * 256 + jt * 16 + lq;
        int k0 = kk * 32 + quad * 8;
        f16x8 v;
#pragma unroll
        for (int e = 0; e < 8; ++e) v[e] = (f16)w_ih[n * 384 + k0 + e];
        *(f16x8*)&w_ihB[(blk * 64 + lane) * 8] = v;
    } else if (blk < 960) {                // wpkE / wpkD: [r6][i32][tid512]
        int i2 = blk - 576;
        const float* src = w_hh; unsigned int* dst = wpkE;
        if (i2 >= 192) { i2 -= 192; src = dec_w_hh; dst = wpkD; }
        int r = i2 >> 5, i = i2 & 31;
#pragma unroll
        for (int c = 0; c < 8; ++c) {
            int tidx = lane * 8 + c;
            int jt = tidx >> 2, q = tidx & 3;
            int n = (r >> 1) * 256 + (r & 1) * 128 + jt;
            int k = q * 64 + 2 * i;
            dst[(r * 32 + i) * 512 + tidx] = pk2(src[n * 256 + k], src[n * 256 + k + 1]);
        }
    } else if (blk < 972) {                // c01 decoder column-half sums
        int n = (blk - 960) * 64 + lane;
        float s0 = 0.f, s1 = 0.f;
        const float* row = dec_w_ih + (long)n * 256;
        for (int d = 0; d < 128; ++d) { s0 += row[d]; s1 += row[128 + d]; }
        c01[n] = s0; c01[768 + n] = s1;
    } else if (blk < 1484) {               // lin transposes
        int i = blk - 972; int mat = i >> 8, d = i & 255;
        const float* src = mat ? tg_lin_w : fg_lin_w;
        float* dst = mat ? linTt : linTf;
#pragma unroll
        for (int c = 0; c < 4; ++c) { int n = lane + 64 * c; dst[d * 256 + n] = src[n * 256 + d]; }
    } else if (blk < 1740) {               // recT
        int d = blk - 1484;
#pragma unroll
        for (int c = 0; c < 2; ++c) { int j2 = lane + 64 * c; recT[d * 128 + j2] = rec_fc_w[j2 * 256 + d]; }
    } else {                               // convT, blk < 2636
        int i = blk - 1740;
#pragma unroll
        for (int c = 0; c < 2; ++c) { int co = lane + 64 * c; convT[i * 128 + co] = conv_w[co * 896 + i]; }
    }
}

// ---------------------------------------------------------------------------
// K1: Conv1d (KS=7, pad 3) + ReLU -> h_catT[t][b][0:128] and xconvT[b][feat][w]
// ---------------------------------------------------------------------------
__global__ void conv_kernel(const float* __restrict__ x,
                            const float* __restrict__ convT,
                            const float* __restrict__ cb,
                            float* __restrict__ h_catT,
                            float* __restrict__ xconvT)
{
    const int wc = blockIdx.x, b = blockIdx.y, tid = threadIdx.x;
    __shared__ float xs[14][128];
    const int w0 = wc * 8;
#pragma unroll
    for (int i = 0; i < 14; ++i) {
        int row = w0 - 3 + i;
        xs[i][tid] = (row >= 0 && row < 128) ? x[(b * 128 + row) * 128 + tid] : 0.f;
    }
    __syncthreads();
    float bias = cb[tid];
    float acc[8];
#pragma unroll
    for (int j = 0; j < 8; ++j) acc[j] = bias;
    for (int ci = 0; ci < 128; ++ci) {
        float wv[7];
#pragma unroll
        for (int t = 0; t < 7; ++t) wv[t] = convT[(ci * 7 + t) * 128 + tid];
#pragma unroll
        for (int t = 0; t < 7; ++t) {
#pragma unroll
            for (int j = 0; j < 8; ++j) acc[j] += xs[j + t][ci] * wv[t];
        }
    }
#pragma unroll
    for (int j = 0; j < 8; ++j) {
        float v = fmaxf(acc[j], 0.f);
        h_catT[((w0 + j) * 16 + b) * 384 + tid] = v;
        xconvT[(b * 128 + tid) * 128 + w0 + j] = v;
    }
}

// ---------------------------------------------------------------------------
// K2: GATv2 lin projection, factored: P = v@Wl^T + b, Q = v@Wr^T
// ---------------------------------------------------------------------------
__global__ void lin_kernel(const float* __restrict__ vsrc, int mode,
                           const float* __restrict__ T,
                           const float* __restrict__ lb,
                           float* __restrict__ P, float* __restrict__ Q)
{
    const int tid = threadIdx.x;
    const int row0 = blockIdx.x * 8;
    __shared__ __align__(16) float vs[8][128];
    if (mode == 0) {
        ((float4*)vs)[tid] = ((const float4*)(vsrc + row0 * 128))[tid];
    } else {
        int b = row0 >> 7;
        int rr = tid >> 5, q = tid & 31;
        int t = (row0 & 127) + rr;
        *(float4*)&vs[rr][q * 4] = *(const float4*)&vsrc[(t * 16 + b) * 384 + q * 4];
    }
    __syncthreads();
    const int n = tid;
    float bias = lb[n];
    float accP[8], accQ[8];
#pragma unroll
    for (int rr = 0; rr < 8; ++rr) { accP[rr] = bias; accQ[rr] = 0.f; }
    for (int d4 = 0; d4 < 32; ++d4) {
        float4 vv[8];
#pragma unroll
        for (int rr = 0; rr < 8; ++rr) vv[rr] = *(const float4*)&vs[rr][d4 * 4];
#pragma unroll
        for (int e = 0; e < 4; ++e) {
            float wP = T[(d4 * 4 + e) * 256 + n];
            float wQ = T[(128 + d4 * 4 + e) * 256 + n];
#pragma unroll
            for (int rr = 0; rr < 8; ++rr) {
                float h = (e == 0) ? vv[rr].x : (e == 1) ? vv[rr].y : (e == 2) ? vv[rr].z : vv[rr].w;
                accP[rr] += h * wP;
                accQ[rr] += h * wQ;
            }
        }
    }
#pragma unroll
    for (int rr = 0; rr < 8; ++rr) {
        P[(long)(row0 + rr) * 256 + n] = accP[rr];
        Q[(long)(row0 + rr) * 256 + n] = accQ[rr];
    }
}

// ---------------------------------------------------------------------------
// K3: GAT attention. grid 2048 (b,i), block 256.
// ---------------------------------------------------------------------------
__global__ void gat_kernel(const float* __restrict__ P, const float* __restrict__ Q,
                           const float* __restrict__ a,
                           const float* __restrict__ bias,
                           const float* __restrict__ vbase,
                           float* __restrict__ h_catT, int mode)
{
    const int bid = blockIdx.x;
    const int b = bid >> 7, i = bid & 127;
    const int tid = threadIdx.x;
    __shared__ __align__(16) float Ps[256], as_[256], ej[128], red[8], op[256];
    __shared__ __align__(16) float buf[16384];

    Ps[tid]  = P[(long)(b * 128 + i) * 256 + tid];
    as_[tid] = a[tid];

    const int jl = tid >> 3, c = tid & 7;
    for (int j0 = 0; j0 < 128; j0 += 32) {
        __syncthreads();
#pragma unroll
        for (int r = 0; r < 8; ++r) {
            int flat = r * 256 + tid;
            int jj = flat >> 6, e4 = flat & 63;
            *(float4*)&buf[jj * 264 + e4 * 4] =
                *(const float4*)&Q[(long)(b * 128 + j0 + jj) * 256 + e4 * 4];
        }
        __syncthreads();
        float p = 0.f;
        for (int k = 0; k < 32; ++k) {
            int e = c + 8 * k;
            float hv = Ps[e] + buf[jl * 264 + e];
            hv = (hv > 0.f) ? hv : 0.2f * hv;
            p += hv * as_[e];
        }
        p += __shfl_xor(p, 1);
        p += __shfl_xor(p, 2);
        p += __shfl_xor(p, 4);
        if (c == 0) ej[j0 + jl] = p + bias[i * 128 + j0 + jl];
    }
    __syncthreads();
    {   // softmax over 128
        float v = (tid < 128) ? ej[tid] : -1e30f;
#pragma unroll
        for (int off = 32; off >= 1; off >>= 1) v = fmaxf(v, __shfl_xor(v, off));
        if ((tid & 63) == 0) red[tid >> 6] = v;
        __syncthreads();
        float m = fmaxf(fmaxf(red[0], red[1]), fmaxf(red[2], red[3]));
        float p = (tid < 128) ? __expf(ej[tid] - m) : 0.f;
        float s = p;
#pragma unroll
        for (int off = 32; off >= 1; off >>= 1) s += __shfl_xor(s, off);
        if ((tid & 63) == 0) red[4 + (tid >> 6)] = s;
        __syncthreads();
        float rs = fast_rcp(red[4] + red[5] + red[6] + red[7]);
        if (tid < 128) ej[tid] = p * rs;
        __syncthreads();
    }
    if (mode == 0) {
        const float4* s = (const float4*)(vbase + (long)b * 16384);
#pragma unroll
        for (int i2 = 0; i2 < 16; ++i2) ((float4*)buf)[i2 * 256 + tid] = s[i2 * 256 + tid];
    } else {
        int row = tid >> 1, hf = tid & 1;
#pragma unroll
        for (int i2 = 0; i2 < 16; ++i2) {
            int cc = (hf * 16 + i2) * 4;
            *(float4*)&buf[row * 128 + cc] = *(const float4*)&vbase[(row * 16 + b) * 384 + cc];
        }
    }
    __syncthreads();
    const int half = tid >> 7, d = tid & 127;
    float p0 = 0.f, p1 = 0.f, p2 = 0.f, p3 = 0.f;
#pragma unroll 4
    for (int j = 0; j < 64; j += 4) {
        int jb = half * 64 + j;
        p0 += ej[jb]     * buf[(jb)     * 128 + d];
        p1 += ej[jb + 1] * buf[(jb + 1) * 128 + d];
        p2 += ej[jb + 2] * buf[(jb + 2) * 128 + d];
        p3 += ej[jb + 3] * buf[(jb + 3) * 128 + d];
    }
    op[tid] = (p0 + p1) + (p2 + p3);
    __syncthreads();
    if (tid < 128) {
        float o = sigmoidf(op[tid] + op[tid + 128]);
        if (mode == 0)
            h_catT[(tid * 16 + b) * 384 + 128 + i] = o;
        else
            h_catT[(i * 16 + b) * 384 + 256 + tid] = o;
    }
}

// ---------------------------------------------------------------------------
// K4: gi GEMM via MFMA -> f32 gi[b][t][768]. grid 128 (t), block 256.
// ---------------------------------------------------------------------------
__global__ void __launch_bounds__(256)
gi_gemm32(const float* __restrict__ h_catT, const f16* __restrict__ w_ihB,
          const float* __restrict__ b_ih, float* __restrict__ gi)
{
    const int t = blockIdx.x, tid = threadIdx.x;
    const int w = tid >> 6, lane = tid & 63, quad = lane >> 4, lq = lane & 15;
    __shared__ __align__(16) f16 hA[16][392];
    {
        int rr = tid >> 4, ii = tid & 15;
#pragma unroll
        for (int i2 = 0; i2 < 6; ++i2) {
            int cc = (ii * 6 + i2) * 4;
            float4 v = *(const float4*)&h_catT[(t * 16 + rr) * 384 + cc];
            f16x4 h; h[0] = (f16)v.x; h[1] = (f16)v.y; h[2] = (f16)v.z; h[3] = (f16)v.w;
            *(f16x4*)&hA[rr][cc] = h;
        }
    }
    int nidx[12];
    float biasv[12];
#pragma unroll
    for (int ti = 0; ti < 12; ++ti) {
        int tau = w * 12 + ti, g = tau % 3, jt = tau / 3;
        nidx[ti] = g * 256 + jt * 16 + lq;
        biasv[ti] = b_ih[nidx[ti]];
    }
    f32x4 acc[12] = {};
    __syncthreads();
    for (int kk = 0; kk < 12; ++kk) {
        f16x8 A = *(const f16x8*)&hA[lq][kk * 32 + quad * 8];
#pragma unroll
        for (int ti = 0; ti < 12; ++ti) {
            f16x8 B = *(const f16x8*)&w_ihB[(((w * 12 + ti) * 12 + kk) * 64 + lane) * 8];
            acc[ti] = __builtin_amdgcn_mfma_f32_16x16x32_f16(A, B, acc[ti], 0, 0, 0);
        }
    }
#pragma unroll
    for (int ti = 0; ti < 12; ++ti)
#pragma unroll
        for (int r = 0; r < 4; ++r) {
            int m = quad * 4 + r;
            gi[((long)m * 128 + t) * 768 + nidx[ti]] = acc[ti][r] + biasv[ti];
        }
}

// ---------------------------------------------------------------------------
// K5a: encoder GRU, 16 blocks (1/batch/CU), 512 thr. tid=(jt*4+q); thread
// computes 6 gate rows {r,z,n}x{jt,128+jt} over quarter-k [q*64,q*64+64):
// h-read per thread = 128 B (8 ds_read_b128) -> halves R7's LDS-pipe load
// (the measured bottleneck). 4-thread reduce via DPP quad_perm (VALU, zero
// LDS). hpk padded per-quarter (+8 f16) to kill 4-way bank alias.
// ---------------------------------------------------------------------------
__global__ void __launch_bounds__(512, 2)
gru_enc(const float* __restrict__ gi,
        const unsigned int* __restrict__ wpk,
        const float* __restrict__ b_hh,
        float* __restrict__ h_end)
{
    const int b = blockIdx.x, tid = threadIdx.x;
    const int jt = tid >> 2, q = tid & 3;
    __shared__ __align__(16) unsigned short hpk[2][296]; // 4 regions x 72 f16 (64+8 pad)
    __shared__ __align__(16) float gich[32 * 768];       // 96KB staging

    unsigned int wr[6][32];
    float bh[6];
    int nidx[6];
#pragma unroll
    for (int r = 0; r < 6; ++r) {
        nidx[r] = (r >> 1) * 256 + (r & 1) * 128 + jt;
        bh[r] = b_hh[nidx[r]];
#pragma unroll
        for (int i = 0; i < 32; ++i) wr[r][i] = wpk[(r * 32 + i) * 512 + tid];
    }
    for (int i = tid; i < 2 * 296; i += 512) ((unsigned short*)hpk)[i] = 0;
    float h0 = 0.f, h1 = 0.f;
    const float* gib = gi + (long)b * 128 * 768;

    for (int cchunk = 0; cchunk < 4; ++cchunk) {
        const float* gsrc = gib + (long)cchunk * 32 * 768;
#pragma unroll
        for (int i = 0; i < 12; ++i) {
            int idx = (i * 512 + tid) * 4;
            *(float4*)&gich[idx] = *(const float4*)&gsrc[idx];
        }
        __syncthreads();
        for (int tt = 0; tt < 32; ++tt) {
            const int t = cchunk * 32 + tt;
            const int par = t & 1;
            float gv[6];
#pragma unroll
            for (int r = 0; r < 6; ++r) gv[r] = gich[tt * 768 + nidx[r]];
            float aa[6][2] = {};
            const ui4* hp = (const ui4*)&hpk[par][q * 72];
#pragma unroll
            for (int i = 0; i < 8; ++i) {
                ui4 hv = hp[i];
#pragma unroll
                for (int e = 0; e < 4; ++e) {
#pragma unroll
                    for (int r = 0; r < 6; ++r)
                        aa[r][e & 1] = dot2f(wr[r][i * 4 + e], hv[e], aa[r][e & 1]);
                }
            }
            float s[6];
#pragma unroll
            for (int r = 0; r < 6; ++r) s[r] = quad_reduce(aa[r][0] + aa[r][1]);
            float r0 = sigmoidf(gv[0] + s[0] + bh[0]);
            float r1 = sigmoidf(gv[1] + s[1] + bh[1]);
            float z0 = sigmoidf(gv[2] + s[2] + bh[2]);
            float z1 = sigmoidf(gv[3] + s[3] + bh[3]);
            float n0 = tanh_f(gv[4] + r0 * (s[4] + bh[4]));
            float n1 = tanh_f(gv[5] + r1 * (s[5] + bh[5]));
            h0 = (1.f - z0) * n0 + z0 * h0;
            h1 = (1.f - z1) * n1 + z1 * h1;
            if (q == 0) {
                hpk[par ^ 1][(jt >> 6) * 72 + (jt & 63)]       = f16bits(h0);
                hpk[par ^ 1][(2 + (jt >> 6)) * 72 + (jt & 63)] = f16bits(h1);
            }
            __syncthreads();
        }
    }
    if (q == 0) {
        h_end[b * 256 + jt]       = h0;
        h_end[b * 256 + 128 + jt] = h1;
    }
}

// ---------------------------------------------------------------------------
// K5b: decoder GRU, same structure; input via precomputed C0/C1 column sums:
// giv[r] = e0*c0 + e1*c1 + bi.  Torch gating: n = tanh(giv + r*(s + bh)).
// dec_out buffered in LDS, flushed per 32-step chunk.
// ---------------------------------------------------------------------------
__global__ void __launch_bounds__(512, 2)
gru_dec(const float* __restrict__ h_end,
        const unsigned int* __restrict__ wpk,
        const float* __restrict__ dec_b_hh,
        const float* __restrict__ c01,
        const float* __restrict__ dec_b_ih,
        float* __restrict__ dec_out)
{
    const int b = blockIdx.x, tid = threadIdx.x;
    const int jt = tid >> 2, q = tid & 3;
    __shared__ __align__(16) unsigned short hpk[2][296];
    __shared__ float he[256];
    __shared__ __align__(16) float decbuf[32 * 256];    // 32KB

    unsigned int wr[6][32];
    float bh[6], c0[6], c1[6], bi[6];
    int nidx[6];
#pragma unroll
    for (int r = 0; r < 6; ++r) {
        nidx[r] = (r >> 1) * 256 + (r & 1) * 128 + jt;
        bh[r] = dec_b_hh[nidx[r]];
        bi[r] = dec_b_ih[nidx[r]];
        c0[r] = c01[nidx[r]];
        c1[r] = c01[768 + nidx[r]];
#pragma unroll
        for (int i = 0; i < 32; ++i) wr[r][i] = wpk[(r * 32 + i) * 512 + tid];
    }
    for (int i = tid; i < 2 * 296; i += 512) ((unsigned short*)hpk)[i] = 0;
    if (tid < 256) he[tid] = h_end[b * 256 + tid];
    float h0 = 0.f, h1 = 0.f;
    __syncthreads();

    for (int cchunk = 0; cchunk < 4; ++cchunk) {
        for (int tt = 0; tt < 32; ++tt) {
            const int t = cchunk * 32 + tt;
            const int par = t & 1;
            float e0 = he[2 * t], e1 = he[2 * t + 1];
            float aa[6][2] = {};
            const ui4* hp = (const ui4*)&hpk[par][q * 72];
#pragma unroll
            for (int i = 0; i < 8; ++i) {
                ui4 hv = hp[i];
#pragma unroll
                for (int e = 0; e < 4; ++e) {
#pragma unroll
                    for (int r = 0; r < 6; ++r)
                        aa[r][e & 1] = dot2f(wr[r][i * 4 + e], hv[e], aa[r][e & 1]);
                }
            }
            float s[6], giv[6];
#pragma unroll
            for (int r = 0; r < 6; ++r) {
                s[r] = quad_reduce(aa[r][0] + aa[r][1]);
                giv[r] = e0 * c0[r] + e1 * c1[r] + bi[r];
            }
            float r0 = sigmoidf(giv[0] + s[0] + bh[0]);
            float r1 = sigmoidf(giv[1] + s[1] + bh[1]);
            float z0 = sigmoidf(giv[2] + s[2] + bh[2]);
            float z1 = sigmoidf(giv[3] + s[3] + bh[3]);
            float n0 = tanh_f(giv[4] + r0 * (s[4] + bh[4]));
            float n1 = tanh_f(giv[5] + r1 * (s[5] + bh[5]));
            h0 = (1.f - z0) * n0 + z0 * h0;
            h1 = (1.f - z1) * n1 + z1 * h1;
            if (q == 0) {
                hpk[par ^ 1][(jt >> 6) * 72 + (jt & 63)]       = f16bits(h0);
                hpk[par ^ 1][(2 + (jt >> 6)) * 72 + (jt & 63)] = f16bits(h1);
                decbuf[tt * 256 + jt]       = h0;
                decbuf[tt * 256 + 128 + jt] = h1;
            }
            __syncthreads();
        }
#pragma unroll
        for (int i = 0; i < 4; ++i) {
            int idx = (i * 512 + tid) * 4;
            *(float4*)&dec_out[(long)b * 32768 + cchunk * 8192 + idx] = *(const float4*)&decbuf[idx];
        }
        __syncthreads();
    }
}

// ---------------------------------------------------------------------------
// K6: forecast MLP. grid 16, block 256.
// ---------------------------------------------------------------------------
__global__ void mlp_kernel(const float* __restrict__ h_end,
                           const float* __restrict__ fc1_w,
                           const float* __restrict__ fc1_b,
                           const float* __restrict__ fc2_w,
                           const float* __restrict__ fc2_b,
                           float* __restrict__ out)
{
    const int b = blockIdx.x, tid = threadIdx.x;
    __shared__ __align__(16) float hv[256], hid[256];
    hv[tid] = h_end[b * 256 + tid];
    __syncthreads();
    float acc = fc1_b[tid], acc2 = 0.f;
    const float4* wr = (const float4*)(fc1_w + tid * 256);
#pragma unroll 4
    for (int i = 0; i < 64; i += 2) {
        float4 w0 = wr[i], w1 = wr[i + 1];
        float4 h0 = *(const float4*)&hv[i * 4], h1 = *(const float4*)&hv[i * 4 + 4];
        acc  += w0.x * h0.x + w0.y * h0.y + w0.z * h0.z + w0.w * h0.w;
        acc2 += w1.x * h1.x + w1.y * h1.y + w1.z * h1.z + w1.w * h1.w;
    }
    hid[tid] = fmaxf(acc + acc2, 0.f);
    __syncthreads();
    if (tid < 128) {
        float a2 = fc2_b[tid], a3 = 0.f;
        const float4* w2 = (const float4*)(fc2_w + tid * 256);
#pragma unroll 4
        for (int i = 0; i < 64; i += 2) {
            float4 w0 = w2[i], w1 = w2[i + 1];
            float4 h0 = *(const float4*)&hid[i * 4], h1 = *(const float4*)&hid[i * 4 + 4];
            a2 += w0.x * h0.x + w0.y * h0.y + w0.z * h0.z + w0.w * h0.w;
            a3 += w1.x * h1.x + w1.y * h1.y + w1.z * h1.z + w1.w * h1.w;
        }
        out[b * 128 + tid] = a2 + a3;
    }
}

// ---------------------------------------------------------------------------
// K7: recons = dec_out @ rec_fc_w^T + b. grid 256 (8 rows), block 256.
// ---------------------------------------------------------------------------
__global__ void recon_kernel(const float* __restrict__ dec_out,
                             const float* __restrict__ recT,
                             const float* __restrict__ rec_b,
                             float* __restrict__ out)
{
    const int blk = blockIdx.x, tid = threadIdx.x;
    __shared__ __align__(16) float dv[8][256];
#pragma unroll
    for (int i = 0; i < 2; ++i)
        ((float4*)dv)[i * 256 + tid] = ((const float4*)(dec_out + blk * 2048))[i * 256 + tid];
    __syncthreads();
    const int j = tid & 127, rh = tid >> 7;
    float acc[4];
#pragma unroll
    for (int rr = 0; rr < 4; ++rr) acc[rr] = rec_b[j];
    for (int d4 = 0; d4 < 64; ++d4) {
        float4 vv[4];
#pragma unroll
        for (int rr = 0; rr < 4; ++rr) vv[rr] = *(const float4*)&dv[rh * 4 + rr][d4 * 4];
#pragma unroll
        for (int e = 0; e < 4; ++e) {
            float wv = recT[(d4 * 4 + e) * 128 + j];
#pragma unroll
            for (int rr = 0; rr < 4; ++rr) {
                float h = (e == 0) ? vv[rr].x : (e == 1) ? vv[rr].y : (e == 2) ? vv[rr].z : vv[rr].w;
                acc[rr] += h * wv;
            }
        }
    }
#pragma unroll
    for (int rr = 0; rr < 4; ++rr)
        out[(blk * 8 + rh * 4 + rr) * 128 + j] = acc[rr];
}

// ---------------------------------------------------------------------------
extern "C" void kernel_launch(void* const* d_in, const int* in_sizes, int n_in,
                              void* d_out, int out_size, void* d_ws, size_t ws_size,
                              hipStream_t stream)
{
    const float* x        = (const float*)d_in[0];
    const float* conv_w   = (const float*)d_in[1];
    const float* conv_b   = (const float*)d_in[2];
    const float* fg_lin_w = (const float*)d_in[3];
    const float* fg_lin_b = (const float*)d_in[4];
    const float* fg_a     = (const float*)d_in[5];
    const float* fg_bias  = (const float*)d_in[6];
    const float* tg_lin_w = (const float*)d_in[7];
    const float* tg_lin_b = (const float*)d_in[8];
    const float* tg_a     = (const float*)d_in[9];
    const float* tg_bias  = (const float*)d_in[10];
    const float* gru_w_ih = (const float*)d_in[11];
    const float* gru_w_hh = (const float*)d_in[12];
    const float* gru_b_ih = (const float*)d_in[13];
    const float* gru_b_hh = (const float*)d_in[14];
    const float* fc1_w    = (const float*)d_in[15];
    const float* fc1_b    = (const float*)d_in[16];
    const float* fc2_w    = (const float*)d_in[17];
    const float* fc2_b    = (const float*)d_in[18];
    const float* dec_w_ih = (const float*)d_in[19];
    const float* dec_w_hh = (const float*)d_in[20];
    const float* dec_b_ih = (const float*)d_in[21];
    const float* dec_b_hh = (const float*)d_in[22];
    const float* rec_fc_w = (const float*)d_in[23];
    const float* rec_fc_b = (const float*)d_in[24];
    float* out = (float*)d_out;

    float* ws      = (float*)d_ws;
    float* h_catT  = ws;
    float* xconvT  = ws + 786432;
    float* Pf      = ws + 1048576;
    float* Qf      = ws + 1572864;
    float* Pt      = ws + 2097152;
    float* Qt      = ws + 2621440;
    float* gi      = Pf;
    f16*   w_ihB   = (f16*)(ws + 3932160);
    unsigned int* wpkE = (unsigned int*)(ws + 4079616);
    unsigned int* wpkD = (unsigned int*)(ws + 4177920);
    float* c01     = ws + 4276224;
    float* linTf   = ws + 4374528;
    float* linTt   = ws + 4440064;
    float* recT    = ws + 4505600;
    float* h_end   = ws + 4538368;
    float* dec_out = ws + 4542464;
    float* convT   = dec_out;

    prep_kernel<<<2636, 64, 0, stream>>>(conv_w, fg_lin_w, tg_lin_w, gru_w_ih, gru_w_hh,
                                         dec_w_ih, dec_w_hh, rec_fc_w,
                                         w_ihB, wpkE, wpkD, c01, linTf, linTt, recT, convT);
    conv_kernel<<<dim3(16, 16), 128, 0, stream>>>(x, convT, conv_b, h_catT, xconvT);
    lin_kernel<<<256, 256, 0, stream>>>(xconvT, 0, linTf, fg_lin_b, Pf, Qf);
    lin_kernel<<<256, 256, 0, stream>>>(h_catT, 1, linTt, tg_lin_b, Pt, Qt);
    gat_kernel<<<2048, 256, 0, stream>>>(Pf, Qf, fg_a, fg_bias, xconvT, h_catT, 0);
    gat_kernel<<<2048, 256, 0, stream>>>(Pt, Qt, tg_a, tg_bias, h_catT, h_catT, 1);
    gi_gemm32<<<128, 256, 0, stream>>>(h_catT, w_ihB, gru_b_ih, gi);
    gru_enc<<<16, 512, 0, stream>>>(gi, wpkE, gru_b_hh, h_end);
    mlp_kernel<<<16, 256, 0, stream>>>(h_end, fc1_w, fc1_b, fc2_w, fc2_b, out);
    gru_dec<<<16, 512, 0, stream>>>(h_end, wpkD, dec_b_hh, c01, dec_b_ih, dec_out);
    recon_kernel<<<256, 256, 0, stream>>>(dec_out, recT, rec_fc_b, out + 2048);
}